// Round 1
// baseline (823.232 us; speedup 1.0000x reference)
//
#include <hip/hip_runtime.h>
#include <math.h>

// ---------------- problem constants ----------------
#define BB    8
#define HH    128
#define WW    128
#define DIM   96
#define MED   192
#define HWPX  16384        // H*W
#define FWH   65
#define RS    129          // LDS row stride in float2 for the 128x128 plane

// workspace layout (float offsets)
#define P_OFF     0
#define P_SZ      (8*192*16384)            // 25,165,824 : x_pre / xsp planes [b][m][h][w]
#define FILT_OFF  (P_OFF + P_SZ)
#define FILT_SZ   (3*192*128*65*2)         // 9,584,640  : filt [s][m][fh][fw] complex
#define GS_OFF    (FILT_OFF + FILT_SZ)     // gctx sums  8*96
#define SS_OFF    (GS_OFF + 768)           // sctx sums  8*48
#define R_OFF     (SS_OFF + 384)           // r          8*3*192

// ---------------- complex helpers ----------------
__device__ __forceinline__ float2 cadd(float2 a, float2 b){ return make_float2(a.x+b.x, a.y+b.y); }
__device__ __forceinline__ float2 csub(float2 a, float2 b){ return make_float2(a.x-b.x, a.y-b.y); }
__device__ __forceinline__ float2 cmul(float2 a, float2 b){ return make_float2(a.x*b.x - a.y*b.y, a.x*b.y + a.y*b.x); }
__device__ __forceinline__ float2 cmulc(float2 a, float2 b){ // a * conj(b)
  return make_float2(a.x*b.x + a.y*b.y, a.y*b.x - a.x*b.y);
}

// =====================================================================
// K_route1: gctx partial sums (mean of x) + sctx partial sums
//           (relu(BN(x @ sp_w^T)) summed over pixels)
// grid 512 = 8 b * 64 chunks(256 px) ; block 256
// =====================================================================
__global__ __launch_bounds__(256) void k_route1(
    const float* __restrict__ x, const float* __restrict__ sp_w,
    const float* __restrict__ bn_gamma, const float* __restrict__ bn_beta,
    const float* __restrict__ bn_mean, const float* __restrict__ bn_var,
    float* __restrict__ gsum, float* __restrict__ ssum)
{
  __shared__ __align__(16) float xt[96*68];    // x tile transposed [c][p(64)+pad]
  __shared__ __align__(16) float spwt[96*52];  // sp_w transposed [c][s(48)+pad]
  __shared__ float sacc[48];
  int t = threadIdx.x;
  int b = blockIdx.x >> 6;
  int chunk = blockIdx.x & 63;
  int p0 = chunk * 256;

  for (int i = t; i < 48*96; i += 256) { int s = i/96, c = i%96; spwt[c*52+s] = sp_w[i]; }
  if (t < 48) sacc[t] = 0.f;

  int sg  = t >> 4;           // 0..11 (t<192 active in matmul)
  int pi4 = (t & 15) * 4;
  float bnA[4], bnB[4];
  if (t < 192) {
    #pragma unroll
    for (int q=0;q<4;q++){
      int s = sg*4+q;
      float a = bn_gamma[s] * rsqrtf(bn_var[s] + 1e-5f);
      bnA[q]=a; bnB[q]=bn_beta[s] - bn_mean[s]*a;
    }
  }
  float greg = 0.f;
  float sreg[4] = {0.f,0.f,0.f,0.f};

  for (int tile = 0; tile < 4; ++tile) {
    __syncthreads();
    const float* src = x + ((size_t)b*HWPX + p0 + tile*64) * 96;
    for (int i = t; i < 64*96/4; i += 256) {
      float4 v = ((const float4*)src)[i];
      int flat = i*4; int p = flat/96, c = flat%96;
      xt[(c+0)*68+p]=v.x; xt[(c+1)*68+p]=v.y; xt[(c+2)*68+p]=v.z; xt[(c+3)*68+p]=v.w;
    }
    __syncthreads();
    if (t < 96) {  // gctx partial: column sum
      const float4* col = (const float4*)&xt[t*68];
      float s0=0,s1=0,s2=0,s3=0;
      #pragma unroll
      for (int j=0;j<16;j++){ float4 v = col[j]; s0+=v.x; s1+=v.y; s2+=v.z; s3+=v.w; }
      greg += (s0+s1)+(s2+s3);
    }
    if (t < 192) { // 64px x 48s GEMM tile, 4x4 register tile
      float acc[4][4] = {};
      for (int c = 0; c < 96; ++c) {
        float4 xv = *(const float4*)&xt[c*68 + pi4];
        float4 wv = *(const float4*)&spwt[c*52 + sg*4];
        float xa[4] = {xv.x,xv.y,xv.z,xv.w};
        float wa[4] = {wv.x,wv.y,wv.z,wv.w};
        #pragma unroll
        for (int ii=0;ii<4;ii++)
          #pragma unroll
          for (int jj=0;jj<4;jj++)
            acc[ii][jj] = fmaf(xa[ii], wa[jj], acc[ii][jj]);
      }
      #pragma unroll
      for (int q=0;q<4;q++)
        #pragma unroll
        for (int pp=0;pp<4;pp++) {
          float yb = acc[pp][q]*bnA[q] + bnB[q];
          sreg[q] += fmaxf(yb, 0.f);
        }
    }
  }
  __syncthreads();
  if (t < 192) { for (int q=0;q<4;q++) atomicAdd(&sacc[sg*4+q], sreg[q]); }
  if (t < 96) atomicAdd(&gsum[b*96+t], greg);
  __syncthreads();
  if (t < 48) atomicAdd(&ssum[b*48+t], sacc[t]);
}

// =====================================================================
// K_pw1: x_pre = Soa(x @ w1^T) written planar P[b][m][h][w]
// grid 3072 = 8 b * 128 h * 3 m-chunks(64) ; block 256
// =====================================================================
__global__ __launch_bounds__(256) void k_pw1(
    const float* __restrict__ x, const float* __restrict__ w1,
    const float* __restrict__ soa_scale, const float* __restrict__ soa_bias,
    float* __restrict__ P)
{
  __shared__ __align__(16) float xs[96*132];   // x row transposed [c][p(128)+pad]
  __shared__ __align__(16) float w1t[96*64];   // w1 chunk transposed [c][m(64)]
  int t = threadIdx.x;
  int bx = blockIdx.x;
  int mq = bx % 3; int h = (bx/3) & 127; int b = bx / 384;

  const float* src = x + ((size_t)b*HWPX + h*128) * 96;
  for (int i = t; i < 128*96/4; i += 256) {
    float4 v = ((const float4*)src)[i];
    int flat = 4*i; int p = flat/96, c = flat%96;
    xs[(c+0)*132+p]=v.x; xs[(c+1)*132+p]=v.y; xs[(c+2)*132+p]=v.z; xs[(c+3)*132+p]=v.w;
  }
  for (int i = t; i < 64*96; i += 256) {
    int c = i / 64, mr = i % 64;
    w1t[c*64+mr] = w1[(mq*64+mr)*96 + c];
  }
  __syncthreads();

  int pq4 = (t & 31) * 4;
  int mg8 = (t >> 5) * 8;
  float acc[4][8] = {};
  for (int c = 0; c < 96; ++c) {
    float4 xv = *(const float4*)&xs[c*132 + pq4];
    float4 wa = *(const float4*)&w1t[c*64 + mg8];
    float4 wb = *(const float4*)&w1t[c*64 + mg8 + 4];
    float xa[4] = {xv.x,xv.y,xv.z,xv.w};
    float wv[8] = {wa.x,wa.y,wa.z,wa.w, wb.x,wb.y,wb.z,wb.w};
    #pragma unroll
    for (int ii=0;ii<4;ii++)
      #pragma unroll
      for (int jj=0;jj<8;jj++)
        acc[ii][jj] = fmaf(xa[ii], wv[jj], acc[ii][jj]);
  }
  float sc = soa_scale[0], bi = soa_bias[0];
  __syncthreads();
  // restage [m][p] for coalesced planar write
  #pragma unroll
  for (int mi=0;mi<8;mi++)
    #pragma unroll
    for (int pi=0;pi<4;pi++) {
      float v = fmaxf(acc[pi][mi], 0.f);
      xs[(mg8+mi)*132 + pq4+pi] = sc*v*v + bi;
    }
  __syncthreads();
  for (int i = t; i < 64*128/4; i += 256) {
    int flat = 4*i; int m = flat >> 7; int p = flat & 127;
    float4 v = *(const float4*)&xs[m*132 + p];
    *(float4*)&P[(size_t)(b*192 + mq*64 + m)*HWPX + h*128 + p] = v;
  }
}

// =====================================================================
// K_route2: per-batch MLP + softmax routing weights r[b][3][192]
// =====================================================================
__global__ __launch_bounds__(256) void k_route2(
    const float* __restrict__ gsum, const float* __restrict__ ssum,
    const float* __restrict__ fc1, const float* __restrict__ fc2,
    const float* __restrict__ mlp_scale, const float* __restrict__ mlp_bias,
    float* __restrict__ r_out)
{
  __shared__ float fused[144], hmid[36], rpre[576];
  int t = threadIdx.x, b = blockIdx.x;
  if (t < 96) fused[t] = gsum[b*96+t] * (1.f/16384.f);
  else if (t < 144) fused[t] = ssum[b*48 + (t-96)] * (1.f/16384.f);
  __syncthreads();
  if (t < 36) {
    float a = 0.f;
    for (int i=0;i<144;i++) a = fmaf(fused[i], fc1[t*144+i], a);
    float rr = fmaxf(a, 0.f);
    hmid[t] = mlp_scale[0]*rr*rr + mlp_bias[0];
  }
  __syncthreads();
  for (int o = t; o < 576; o += 256) {
    float a = 0.f;
    for (int j=0;j<36;j++) a = fmaf(hmid[j], fc2[o*36+j], a);
    rpre[o] = a;
  }
  __syncthreads();
  if (t < 192) {
    float v0 = rpre[t], v1 = rpre[192+t], v2 = rpre[384+t];
    float mx = fmaxf(v0, fmaxf(v1, v2));
    float e0 = expf(v0-mx), e1 = expf(v1-mx), e2 = expf(v2-mx);
    float inv = 1.f/(e0+e1+e2);
    r_out[(b*3+0)*192+t] = e0*inv;
    r_out[(b*3+1)*192+t] = e1*inv;
    r_out[(b*3+2)*192+t] = e2*inv;
  }
}

// =====================================================================
// K_filt: bicubic (align_corners, border-replicate) resize of cw_s to
//         [128][65], layout filt[s][m][fh][fw] complex
// grid 384 = 3 s * 128 fh ; block 256
// =====================================================================
__device__ __forceinline__ float cubicw(float tt){
  float t = fabsf(tt), t2=t*t, t3=t2*t;
  if (t <= 1.f) return 1.25f*t3 - 2.25f*t2 + 1.f;
  if (t < 2.f)  return -0.75f*t3 + 3.75f*t2 - 6.f*t + 3.f;
  return 0.f;
}

__global__ __launch_bounds__(256) void k_filt(
    const float* __restrict__ cw0, const float* __restrict__ cw1,
    const float* __restrict__ cw2, float* __restrict__ filt)
{
  int bx = blockIdx.x; int s = bx >> 7; int fh = bx & 127;
  const float* cw = (s==0) ? cw0 : ((s==1) ? cw1 : cw2);
  int SH = (s==0) ? 16 : ((s==1) ? 8 : 24);
  int SW = (s==0) ? 9  : ((s==1) ? 4 : 13);
  float sh = fh * (float)(SH-1) / 127.f;
  int fh0 = (int)floorf(sh);
  float wh[4]; int ih[4];
  #pragma unroll
  for (int k=0;k<4;k++){
    int kk = fh0-1+k;
    wh[k] = cubicw(sh - (float)kk);
    ih[k] = min(max(kk,0), SH-1);
  }
  int t = threadIdx.x;
  for (int i = t; i < 192*65; i += 256) {
    int m = i / 65, fw = i % 65;
    float sw = fw * (float)(SW-1) / 64.f;
    int fw0 = (int)floorf(sw);
    float are=0.f, aim=0.f;
    #pragma unroll
    for (int kb=0;kb<4;kb++){
      int jj = fw0-1+kb;
      float wwb = cubicw(sw - (float)jj);
      int iw = min(max(jj,0), SW-1);
      #pragma unroll
      for (int ka=0;ka<4;ka++){
        const float* p = cw + (size_t)((ih[ka]*SW + iw)*192 + m)*2;
        float wgt = wh[ka]*wwb;
        are = fmaf(wgt, p[0], are);
        aim = fmaf(wgt, p[1], aim);
      }
    }
    *(float2*)&filt[ (size_t)(((s*192+m)*128 + fh)*65 + fw) * 2 ] = make_float2(are, aim);
  }
}

// =====================================================================
// K_spectral: per (b,m) plane: 2D FFT (DIF, fused stage pairs) ->
//   routed spectral multiply (Hermitian mirror; numpy-irfft DC/Nyquist
//   semantics) -> 2D inverse FFT (DIT) -> real part * 1/16384, in place.
// grid 1536 = 8 b * 192 m ; block 256 ; LDS 132.6 KB
// =====================================================================
__device__ __forceinline__ float2 twf(const float* twr, const float* twi, int k){
  return make_float2(twr[k], twi[k]);
}

__device__ void dif_fused(float2* C, const float* twr, const float* twi, int t, int lh, int LS, int PS){
  int h1 = 1 << lh, h2 = h1 >> 1;
  for (int it = 0; it < 16; ++it) {
    int idx = t + 256*it;                 // 4096 groups
    int line = idx & 127; int g = idx >> 7;
    int k = g & (h2-1); int blk = g >> (lh-1);
    int p = blk*(h1<<1) + k;
    int base = line*LS + p*PS;
    float2 x0 = C[base], x1 = C[base + h2*PS], x2 = C[base + h1*PS], x3 = C[base + (h1+h2)*PS];
    float2 u = cadd(x0,x2), d0 = csub(x0,x2);
    float2 s = cadd(x1,x3), d1 = csub(x1,x3);
    float2 w = cmul(d0, twf(twr,twi, k << (6-lh)));
    float2 v = cmul(d1, twf(twr,twi, (k+h2) << (6-lh)));
    float2 t3 = twf(twr,twi, k << (7-lh));
    C[base]             = cadd(u,s);
    C[base + h2*PS]     = cmul(csub(u,s), t3);
    C[base + h1*PS]     = cadd(w,v);
    C[base + (h1+h2)*PS]= cmul(csub(w,v), t3);
  }
}
__device__ void dif_last(float2* C, int t, int LS, int PS){
  for (int it = 0; it < 32; ++it) {
    int idx = t + 256*it;                 // 8192 butterflies, h=1, tw=1
    int line = idx & 127; int j = idx >> 7;
    int base = line*LS + (2*j)*PS;
    float2 u = C[base], v = C[base + PS];
    C[base] = cadd(u,v); C[base+PS] = csub(u,v);
  }
}
__device__ void dit_fused(float2* C, const float* twr, const float* twi, int t, int la, int LS, int PS){
  int h = 1 << la;
  for (int it = 0; it < 16; ++it) {
    int idx = t + 256*it;
    int line = idx & 127; int g = idx >> 7;
    int k = g & (h-1); int blk = g >> la;
    int p = blk*(h<<2) + k;
    int base = line*LS + p*PS;
    float2 x0 = C[base], x1 = C[base + h*PS], x2 = C[base + 2*h*PS], x3 = C[base + 3*h*PS];
    float2 tA = twf(twr,twi, k << (6-la));
    float2 x1t = cmulc(x1, tA), x3t = cmulc(x3, tA);
    float2 u = cadd(x0,x1t), v = csub(x0,x1t);
    float2 s = cadd(x2,x3t), w = csub(x2,x3t);
    float2 st = cmulc(s, twf(twr,twi, k << (5-la)));
    float2 wt = cmulc(w, twf(twr,twi, (k+h) << (5-la)));
    C[base]            = cadd(u, st);
    C[base + 2*h*PS]   = csub(u, st);
    C[base + h*PS]     = cadd(v, wt);
    C[base + 3*h*PS]   = csub(v, wt);
  }
}
__device__ void dit_last(float2* C, const float* twr, const float* twi, int t, int LS, int PS){
  for (int it = 0; it < 32; ++it) {
    int idx = t + 256*it;                 // h=64
    int line = idx & 127; int k = idx >> 7;
    int base = line*LS + k*PS;
    float2 u = C[base], xv = C[base + 64*PS];
    float2 xt = cmulc(xv, twf(twr,twi,k));
    C[base] = cadd(u,xt); C[base+64*PS] = csub(u,xt);
  }
}

__global__ __launch_bounds__(256) void k_spectral(
    float* __restrict__ P, const float* __restrict__ filt, const float* __restrict__ r)
{
  __shared__ __align__(16) float2 C[128*RS];   // 132,096 B
  __shared__ float twr[64], twi[64];
  int t = threadIdx.x;
  int bm = blockIdx.x; int b = bm / 192; int m = bm % 192;
  float* plane = P + (size_t)bm * HWPX;

  if (t < 64) {
    float ang = -6.283185307179586477f * (float)t / 128.f;
    twr[t] = cosf(ang); twi[t] = sinf(ang);
  }
  for (int i = t; i < HWPX; i += 256) {
    int h = i >> 7, w = i & 127;
    C[h*RS + w] = make_float2(plane[i], 0.f);
  }
  float r0 = r[(b*3+0)*192+m];
  float r1 = r[(b*3+1)*192+m];
  float r2 = r[(b*3+2)*192+m];
  __syncthreads();

  // forward rows (along w)
  dif_fused(C,twr,twi,t,6, RS,1); __syncthreads();
  dif_fused(C,twr,twi,t,4, RS,1); __syncthreads();
  dif_fused(C,twr,twi,t,2, RS,1); __syncthreads();
  dif_last (C,t, RS,1);           __syncthreads();
  // forward cols (along h)
  dif_fused(C,twr,twi,t,6, 1,RS); __syncthreads();
  dif_fused(C,twr,twi,t,4, 1,RS); __syncthreads();
  dif_fused(C,twr,twi,t,2, 1,RS); __syncthreads();
  dif_last (C,t, 1,RS);           __syncthreads();

  // spectral multiply (storage is bit-reversed in both dims)
  {
    const float2* fb0 = (const float2*)filt + (size_t)(0*192+m)*8320;
    const float2* fb1 = (const float2*)filt + (size_t)(1*192+m)*8320;
    const float2* fb2 = (const float2*)filt + (size_t)(2*192+m)*8320;
    const float inv = 1.f/16384.f;
    for (int i = t; i < 8320; i += 256) {
      int fh = i / 65, fw = i % 65;
      int off = fh*65 + fw;
      float2 f0 = fb0[off], f1 = fb1[off], f2 = fb2[off];
      float cr = (r0*f0.x + r1*f1.x + r2*f2.x) * inv;
      float ci = (r0*f0.y + r1*f1.y + r2*f2.y) * inv;
      int ib = __brev((unsigned)fh) >> 25;
      int jb = __brev((unsigned)fw) >> 25;
      if (fw == 0 || fw == 64) {
        // numpy irfft ignores imag at DC/Nyquist w-columns:
        // effective filter = (c(fh) + conj(c((128-fh)%128)))/2
        int fh2 = (128 - fh) & 127;
        int off2 = fh2*65 + fw;
        float2 g0 = fb0[off2], g1 = fb1[off2], g2 = fb2[off2];
        float c2r = (r0*g0.x + r1*g1.x + r2*g2.x) * inv;
        float c2i = (r0*g0.y + r1*g1.y + r2*g2.y) * inv;
        float er = 0.5f*(cr + c2r), ei = 0.5f*(ci - c2i);
        float2 X = C[ib*RS + jb];
        C[ib*RS + jb] = make_float2(X.x*er - X.y*ei, X.x*ei + X.y*er);
      } else {
        float2 X = C[ib*RS + jb];
        C[ib*RS + jb] = make_float2(X.x*cr - X.y*ci, X.x*ci + X.y*cr);
        int fh2 = (128 - fh) & 127; int fw2 = 128 - fw;
        int ib2 = __brev((unsigned)fh2) >> 25;
        int jb2 = __brev((unsigned)fw2) >> 25;
        float2 Y = C[ib2*RS + jb2];   // multiply by conj(c)
        C[ib2*RS + jb2] = make_float2(Y.x*cr + Y.y*ci, Y.y*cr - Y.x*ci);
      }
    }
  }
  __syncthreads();

  // inverse cols
  dit_fused(C,twr,twi,t,0, 1,RS); __syncthreads();
  dit_fused(C,twr,twi,t,2, 1,RS); __syncthreads();
  dit_fused(C,twr,twi,t,4, 1,RS); __syncthreads();
  dit_last (C,twr,twi,t, 1,RS);   __syncthreads();
  // inverse rows
  dit_fused(C,twr,twi,t,0, RS,1); __syncthreads();
  dit_fused(C,twr,twi,t,2, RS,1); __syncthreads();
  dit_fused(C,twr,twi,t,4, RS,1); __syncthreads();
  dit_last (C,twr,twi,t, RS,1);   __syncthreads();

  for (int i = t; i < HWPX; i += 256) {
    int h = i >> 7, w = i & 127;
    plane[i] = C[h*RS + w].x;     // 1/16384 already folded into filter
  }
}

// =====================================================================
// K_pw2: out[b,h,w,c] = sum_m xsp[b][m][h][w] * w2[c][m]
// grid 2048 = 8 b * 128 h * 2 c-halves ; block 192
// =====================================================================
__global__ __launch_bounds__(192) void k_pw2(
    const float* __restrict__ P, const float* __restrict__ w2, float* __restrict__ out)
{
  __shared__ __align__(16) float w2t[192*52];  // [m][c(48)+pad]
  __shared__ __align__(16) float xs2[64*132];  // [m(64)][w(128)+pad], reused for out tile
  int t = threadIdx.x;
  int bx = blockIdx.x;
  int ch = bx & 1; int h = (bx >> 1) & 127; int b = bx >> 8;

  for (int i = t; i < 48*192; i += 192) {
    int c = i / 192, m = i % 192;
    w2t[m*52 + c] = w2[(ch*48 + c)*192 + m];
  }
  int wq4 = (t & 31)*4;
  int cg8 = (t >> 5)*8;          // t<192 -> cg in 0..5
  float acc[4][8] = {};
  for (int mc = 0; mc < 3; ++mc) {
    __syncthreads();
    for (int i = t; i < 64*128/4; i += 192) {
      int flat = 4*i; int mm = flat >> 7; int w = flat & 127;
      float4 v = *(const float4*)&P[(size_t)(b*192 + mc*64 + mm)*HWPX + h*128 + w];
      *(float4*)&xs2[mm*132 + w] = v;
    }
    __syncthreads();
    for (int mm = 0; mm < 64; ++mm) {
      float4 xv = *(const float4*)&xs2[mm*132 + wq4];
      int mg = mc*64 + mm;
      float4 wa = *(const float4*)&w2t[mg*52 + cg8];
      float4 wb = *(const float4*)&w2t[mg*52 + cg8 + 4];
      float xa[4] = {xv.x,xv.y,xv.z,xv.w};
      float wv[8] = {wa.x,wa.y,wa.z,wa.w, wb.x,wb.y,wb.z,wb.w};
      #pragma unroll
      for (int ii=0;ii<4;ii++)
        #pragma unroll
        for (int jj=0;jj<8;jj++)
          acc[ii][jj] = fmaf(xa[ii], wv[jj], acc[ii][jj]);
    }
  }
  __syncthreads();
  // restage [w][c] for coalesced channel-last write
  #pragma unroll
  for (int wi=0; wi<4; wi++)
    #pragma unroll
    for (int cj=0; cj<8; cj++)
      xs2[(wq4+wi)*52 + cg8+cj] = acc[wi][cj];
  __syncthreads();
  for (int i = t; i < 128*48/4; i += 192) {
    int flat = 4*i; int w = flat / 48; int c = flat % 48;
    float4 v = *(const float4*)&xs2[w*52 + c];
    *(float4*)&out[((size_t)b*HWPX + h*128 + w)*96 + ch*48 + c] = v;
  }
}

// =====================================================================
extern "C" void kernel_launch(void* const* d_in, const int* in_sizes, int n_in,
                              void* d_out, int out_size, void* d_ws, size_t ws_size,
                              hipStream_t stream) {
  const float* x          = (const float*)d_in[0];
  const float* w1         = (const float*)d_in[1];
  const float* soa1_scale = (const float*)d_in[2];
  const float* soa1_bias  = (const float*)d_in[3];
  const float* cw0        = (const float*)d_in[4];
  const float* cw1        = (const float*)d_in[5];
  const float* cw2        = (const float*)d_in[6];
  const float* sp_w       = (const float*)d_in[7];
  const float* bn_gamma   = (const float*)d_in[8];
  const float* bn_beta    = (const float*)d_in[9];
  const float* bn_mean    = (const float*)d_in[10];
  const float* bn_var     = (const float*)d_in[11];
  const float* fc1        = (const float*)d_in[12];
  const float* mlp_scale  = (const float*)d_in[13];
  const float* mlp_bias   = (const float*)d_in[14];
  const float* fc2        = (const float*)d_in[15];
  const float* w2         = (const float*)d_in[16];
  float* out = (float*)d_out;

  float* ws   = (float*)d_ws;
  float* P    = ws + P_OFF;
  float* filt = ws + FILT_OFF;
  float* gsum = ws + GS_OFF;
  float* ssum = ws + SS_OFF;
  float* rbuf = ws + R_OFF;

  hipMemsetAsync(gsum, 0, (768+384)*sizeof(float), stream);

  k_route1 <<<512,  256, 0, stream>>>(x, sp_w, bn_gamma, bn_beta, bn_mean, bn_var, gsum, ssum);
  k_pw1    <<<3072, 256, 0, stream>>>(x, w1, soa1_scale, soa1_bias, P);
  k_route2 <<<8,    256, 0, stream>>>(gsum, ssum, fc1, fc2, mlp_scale, mlp_bias, rbuf);
  k_filt   <<<384,  256, 0, stream>>>(cw0, cw1, cw2, filt);
  k_spectral<<<1536,256, 0, stream>>>(P, filt, rbuf);
  k_pw2    <<<2048, 192, 0, stream>>>(P, w2, out);
}

// Round 2
// 549.300 us; speedup vs baseline: 1.4987x; 1.4987x over previous
//
#include <hip/hip_runtime.h>
#include <math.h>

// ---------------- problem constants ----------------
#define BB    8
#define HH    128
#define WW    128
#define DIM   96
#define MED   192
#define HWPX  16384        // H*W
#define FWH   65
#define LSTR  67           // LDS row stride (floats), odd -> conflict-free col walk

// workspace layout (float offsets)
#define P_OFF     0
#define P_SZ      (8*192*16384)            // x_pre / xsp planes [b][m][h][w]
#define FILT_OFF  (P_OFF + P_SZ)
#define FILT_SZ   (3*192*128*65*2)         // filt [s][m][fh][fw] complex
#define GS_OFF    (FILT_OFF + FILT_SZ)     // gctx sums  8*96
#define SS_OFF    (GS_OFF + 768)           // sctx sums  8*48
#define R_OFF     (SS_OFF + 384)           // r          8*3*192

// =====================================================================
// K_route1: gctx partial sums + sctx partial sums  (unchanged from R1)
// =====================================================================
__global__ __launch_bounds__(256) void k_route1(
    const float* __restrict__ x, const float* __restrict__ sp_w,
    const float* __restrict__ bn_gamma, const float* __restrict__ bn_beta,
    const float* __restrict__ bn_mean, const float* __restrict__ bn_var,
    float* __restrict__ gsum, float* __restrict__ ssum)
{
  __shared__ __align__(16) float xt[96*68];
  __shared__ __align__(16) float spwt[96*52];
  __shared__ float sacc[48];
  int t = threadIdx.x;
  int b = blockIdx.x >> 6;
  int chunk = blockIdx.x & 63;
  int p0 = chunk * 256;

  for (int i = t; i < 48*96; i += 256) { int s = i/96, c = i%96; spwt[c*52+s] = sp_w[i]; }
  if (t < 48) sacc[t] = 0.f;

  int sg  = t >> 4;
  int pi4 = (t & 15) * 4;
  float bnA[4], bnB[4];
  if (t < 192) {
    #pragma unroll
    for (int q=0;q<4;q++){
      int s = sg*4+q;
      float a = bn_gamma[s] * rsqrtf(bn_var[s] + 1e-5f);
      bnA[q]=a; bnB[q]=bn_beta[s] - bn_mean[s]*a;
    }
  }
  float greg = 0.f;
  float sreg[4] = {0.f,0.f,0.f,0.f};

  for (int tile = 0; tile < 4; ++tile) {
    __syncthreads();
    const float* src = x + ((size_t)b*HWPX + p0 + tile*64) * 96;
    for (int i = t; i < 64*96/4; i += 256) {
      float4 v = ((const float4*)src)[i];
      int flat = i*4; int p = flat/96, c = flat%96;
      xt[(c+0)*68+p]=v.x; xt[(c+1)*68+p]=v.y; xt[(c+2)*68+p]=v.z; xt[(c+3)*68+p]=v.w;
    }
    __syncthreads();
    if (t < 96) {
      const float4* col = (const float4*)&xt[t*68];
      float s0=0,s1=0,s2=0,s3=0;
      #pragma unroll
      for (int j=0;j<16;j++){ float4 v = col[j]; s0+=v.x; s1+=v.y; s2+=v.z; s3+=v.w; }
      greg += (s0+s1)+(s2+s3);
    }
    if (t < 192) {
      float acc[4][4] = {};
      for (int c = 0; c < 96; ++c) {
        float4 xv = *(const float4*)&xt[c*68 + pi4];
        float4 wv = *(const float4*)&spwt[c*52 + sg*4];
        float xa[4] = {xv.x,xv.y,xv.z,xv.w};
        float wa[4] = {wv.x,wv.y,wv.z,wv.w};
        #pragma unroll
        for (int ii=0;ii<4;ii++)
          #pragma unroll
          for (int jj=0;jj<4;jj++)
            acc[ii][jj] = fmaf(xa[ii], wa[jj], acc[ii][jj]);
      }
      #pragma unroll
      for (int q=0;q<4;q++)
        #pragma unroll
        for (int pp=0;pp<4;pp++) {
          float yb = acc[pp][q]*bnA[q] + bnB[q];
          sreg[q] += fmaxf(yb, 0.f);
        }
    }
  }
  __syncthreads();
  if (t < 192) { for (int q=0;q<4;q++) atomicAdd(&sacc[sg*4+q], sreg[q]); }
  if (t < 96) atomicAdd(&gsum[b*96+t], greg);
  __syncthreads();
  if (t < 48) atomicAdd(&ssum[b*48+t], sacc[t]);
}

// =====================================================================
// K_pw1: x_pre = Soa(x @ w1^T) planar P[b][m][h][w]
// Restructured: [p][c] identity staging (conflict-free writes) +
// lane-stride-32 pixel ownership (stride-97 reads == 1 mod 32, free).
// grid 3072 = 8 b * 128 h * 3 m-chunks(64) ; block 256
// =====================================================================
__global__ __launch_bounds__(256) void k_pw1(
    const float* __restrict__ x, const float* __restrict__ w1,
    const float* __restrict__ soa_scale, const float* __restrict__ soa_bias,
    float* __restrict__ P)
{
  __shared__ float xs[128*97];                 // [p][c] pad 96->97
  __shared__ __align__(16) float w1t[96*64];   // [c][m]
  int t = threadIdx.x;
  int bx = blockIdx.x;
  int mq = bx % 3; int h = (bx/3) & 127; int b = bx / 384;

  const float4* src4 = (const float4*)(x + ((size_t)b*HWPX + h*128) * 96);
  for (int i = t; i < 128*96/4; i += 256) {
    float4 v = src4[i];
    int flat = 4*i; int p = flat/96, c = flat%96;
    float* d = &xs[p*97 + c];
    d[0]=v.x; d[1]=v.y; d[2]=v.z; d[3]=v.w;
  }
  for (int i = t; i < 64*96; i += 256) {
    int c = i >> 6, mr = i & 63;
    w1t[c*64+mr] = w1[(mq*64+mr)*96 + c];
  }
  __syncthreads();

  int pl  = t & 31;            // pixels pl, pl+32, pl+64, pl+96
  int mg8 = (t >> 5) * 8;
  float acc[4][8] = {};
  for (int c = 0; c < 96; ++c) {
    float xa[4];
    #pragma unroll
    for (int ii=0;ii<4;ii++) xa[ii] = xs[(pl + 32*ii)*97 + c];
    float4 wa = *(const float4*)&w1t[c*64 + mg8];
    float4 wb = *(const float4*)&w1t[c*64 + mg8 + 4];
    float wv[8] = {wa.x,wa.y,wa.z,wa.w, wb.x,wb.y,wb.z,wb.w};
    #pragma unroll
    for (int ii=0;ii<4;ii++)
      #pragma unroll
      for (int jj=0;jj<8;jj++)
        acc[ii][jj] = fmaf(xa[ii], wv[jj], acc[ii][jj]);
  }
  float sc = soa_scale[0], bi = soa_bias[0];
  __syncthreads();
  // restage [m][p] (conflict-free: lane-distinct banks via pl)
  #pragma unroll
  for (int mi=0;mi<8;mi++)
    #pragma unroll
    for (int ii=0;ii<4;ii++) {
      float v = fmaxf(acc[ii][mi], 0.f);
      xs[(mg8+mi)*128 + pl + 32*ii] = sc*v*v + bi;
    }
  __syncthreads();
  for (int i = t; i < 64*128/4; i += 256) {
    int m = i >> 5; int p4 = (i & 31)*4;
    float4 v = *(const float4*)&xs[m*128 + p4];
    *(float4*)&P[(size_t)(b*192 + mq*64 + m)*HWPX + h*128 + p4] = v;
  }
}

// =====================================================================
// K_route2: per-batch MLP + softmax routing weights (unchanged)
// =====================================================================
__global__ __launch_bounds__(256) void k_route2(
    const float* __restrict__ gsum, const float* __restrict__ ssum,
    const float* __restrict__ fc1, const float* __restrict__ fc2,
    const float* __restrict__ mlp_scale, const float* __restrict__ mlp_bias,
    float* __restrict__ r_out)
{
  __shared__ float fused[144], hmid[36], rpre[576];
  int t = threadIdx.x, b = blockIdx.x;
  if (t < 96) fused[t] = gsum[b*96+t] * (1.f/16384.f);
  else if (t < 144) fused[t] = ssum[b*48 + (t-96)] * (1.f/16384.f);
  __syncthreads();
  if (t < 36) {
    float a = 0.f;
    for (int i=0;i<144;i++) a = fmaf(fused[i], fc1[t*144+i], a);
    float rr = fmaxf(a, 0.f);
    hmid[t] = mlp_scale[0]*rr*rr + mlp_bias[0];
  }
  __syncthreads();
  for (int o = t; o < 576; o += 256) {
    float a = 0.f;
    for (int j=0;j<36;j++) a = fmaf(hmid[j], fc2[o*36+j], a);
    rpre[o] = a;
  }
  __syncthreads();
  if (t < 192) {
    float v0 = rpre[t], v1 = rpre[192+t], v2 = rpre[384+t];
    float mx = fmaxf(v0, fmaxf(v1, v2));
    float e0 = expf(v0-mx), e1 = expf(v1-mx), e2 = expf(v2-mx);
    float inv = 1.f/(e0+e1+e2);
    r_out[(b*3+0)*192+t] = e0*inv;
    r_out[(b*3+1)*192+t] = e1*inv;
    r_out[(b*3+2)*192+t] = e2*inv;
  }
}

// =====================================================================
// K_filt: bicubic resize of cw_s to [128][65] (unchanged)
// =====================================================================
__device__ __forceinline__ float cubicw(float tt){
  float t = fabsf(tt), t2=t*t, t3=t2*t;
  if (t <= 1.f) return 1.25f*t3 - 2.25f*t2 + 1.f;
  if (t < 2.f)  return -0.75f*t3 + 3.75f*t2 - 6.f*t + 3.f;
  return 0.f;
}

__global__ __launch_bounds__(256) void k_filt(
    const float* __restrict__ cw0, const float* __restrict__ cw1,
    const float* __restrict__ cw2, float* __restrict__ filt)
{
  int bx = blockIdx.x; int s = bx >> 7; int fh = bx & 127;
  const float* cw = (s==0) ? cw0 : ((s==1) ? cw1 : cw2);
  int SH = (s==0) ? 16 : ((s==1) ? 8 : 24);
  int SW = (s==0) ? 9  : ((s==1) ? 4 : 13);
  float sh = fh * (float)(SH-1) / 127.f;
  int fh0 = (int)floorf(sh);
  float wh[4]; int ih[4];
  #pragma unroll
  for (int k=0;k<4;k++){
    int kk = fh0-1+k;
    wh[k] = cubicw(sh - (float)kk);
    ih[k] = min(max(kk,0), SH-1);
  }
  int t = threadIdx.x;
  for (int i = t; i < 192*65; i += 256) {
    int m = i / 65, fw = i % 65;
    float sw = fw * (float)(SW-1) / 64.f;
    int fw0 = (int)floorf(sw);
    float are=0.f, aim=0.f;
    #pragma unroll
    for (int kb=0;kb<4;kb++){
      int jj = fw0-1+kb;
      float wwb = cubicw(sw - (float)jj);
      int iw = min(max(jj,0), SW-1);
      #pragma unroll
      for (int ka=0;ka<4;ka++){
        const float* p = cw + (size_t)((ih[ka]*SW + iw)*192 + m)*2;
        float wgt = wh[ka]*wwb;
        are = fmaf(wgt, p[0], are);
        aim = fmaf(wgt, p[1], aim);
      }
    }
    *(float2*)&filt[ (size_t)(((s*192+m)*128 + fh)*65 + fw) * 2 ] = make_float2(are, aim);
  }
}

// =====================================================================
// K_spectral (rewritten): per (b,m) plane, rfft-based.
//  rows: packed 64-pt complex FFT + unpack -> 65-bin half spectrum
//  cols: 65 x 128-pt FFT ; routed multiply ; inverse mirror
//  LDS: split Re/Im, 128 x 67 floats each (68.6 KB) -> 2 blocks/CU
//  block 512 ; grid 1536
// =====================================================================
__device__ __forceinline__ void dif4(float* SR, float* SI,
    const float* twr, const float* twi,
    int a0, int a1, int a2, int a3, int t1, int t2, int t3)
{
  float x0r=SR[a0], x0i=SI[a0], x1r=SR[a1], x1i=SI[a1];
  float x2r=SR[a2], x2i=SI[a2], x3r=SR[a3], x3i=SI[a3];
  float ur = x0r+x2r, ui = x0i+x2i, d0r = x0r-x2r, d0i = x0i-x2i;
  float sr = x1r+x3r, si = x1i+x3i, d1r = x1r-x3r, d1i = x1i-x3i;
  float w1r = twr[t1], w1i = twi[t1];
  float wr_ = d0r*w1r - d0i*w1i, wi_ = d0r*w1i + d0i*w1r;
  float w2r = twr[t2], w2i = twi[t2];
  float vr = d1r*w2r - d1i*w2i, vi = d1r*w2i + d1i*w2r;
  float t3r = twr[t3], t3i = twi[t3];
  SR[a0] = ur+sr;  SI[a0] = ui+si;
  float mr = ur-sr, mi = ui-si;
  SR[a1] = mr*t3r - mi*t3i; SI[a1] = mr*t3i + mi*t3r;
  SR[a2] = wr_+vr; SI[a2] = wi_+vi;
  float nr = wr_-vr, ni = wi_-vi;
  SR[a3] = nr*t3r - ni*t3i; SI[a3] = nr*t3i + ni*t3r;
}

__device__ __forceinline__ void dit4(float* SR, float* SI,
    const float* twr, const float* twi,
    int a0, int a1, int a2, int a3, int tA, int tB, int tC)
{
  float x0r=SR[a0], x0i=SI[a0], x1r=SR[a1], x1i=SI[a1];
  float x2r=SR[a2], x2i=SI[a2], x3r=SR[a3], x3i=SI[a3];
  float war = twr[tA], wai = twi[tA];
  float x1tr = x1r*war + x1i*wai, x1ti = x1i*war - x1r*wai;
  float x3tr = x3r*war + x3i*wai, x3ti = x3i*war - x3r*wai;
  float ur = x0r+x1tr, ui = x0i+x1ti, vr = x0r-x1tr, vi = x0i-x1ti;
  float sr = x2r+x3tr, si = x2i+x3ti, wr_ = x2r-x3tr, wi_ = x2i-x3ti;
  float wbr = twr[tB], wbi = twi[tB];
  float str = sr*wbr + si*wbi, sti = si*wbr - sr*wbi;
  float wcr = twr[tC], wci = twi[tC];
  float wtr = wr_*wcr + wi_*wci, wti = wi_*wcr - wr_*wci;
  SR[a0] = ur+str; SI[a0] = ui+sti;
  SR[a2] = ur-str; SI[a2] = ui-sti;
  SR[a1] = vr+wtr; SI[a1] = vi+wti;
  SR[a3] = vr-wtr; SI[a3] = vi-wti;
}

__global__ __launch_bounds__(512, 4) void k_spectral(
    float* __restrict__ P, const float* __restrict__ filt, const float* __restrict__ r)
{
  __shared__ float SR[128*LSTR];   // 34,304 B
  __shared__ float SI[128*LSTR];   // 34,304 B
  __shared__ float twr[64], twi[64];
  int t = threadIdx.x;
  int bm = blockIdx.x; int b = bm / 192; int m = bm % 192;
  float* plane = P + (size_t)bm * HWPX;

  if (t < 64) {
    float ang = -6.283185307179586477f * (float)t / 128.f;
    twr[t] = cosf(ang); twi[t] = sinf(ang);
  }
  // load + even/odd pack: z[n] = x[2n] + i x[2n+1]
  for (int it = 0; it < 8; ++it) {
    int idx = t + 512*it;                  // 4096 float4s
    int h = idx >> 5, j = idx & 31;
    float4 v = ((const float4*)plane)[idx];
    int base = h*LSTR + 2*j;
    SR[base]   = v.x; SI[base]   = v.y;
    SR[base+1] = v.z; SI[base+1] = v.w;
  }
  float r0 = r[(b*3+0)*192+m];
  float r1 = r[(b*3+1)*192+m];
  float r2 = r[(b*3+2)*192+m];
  __syncthreads();

  // ---- forward rows: 64-pt DIF (3 fused radix-4 passes) ----
  #pragma unroll
  for (int ps = 0; ps < 3; ++ps) {
    const int lh = 5 - 2*ps;               // 5,3,1
    const int h1 = 1 << lh, h2 = h1 >> 1;
    for (int it = 0; it < 4; ++it) {
      int idx = t + 512*it;                // 2048 = 128 rows * 16 groups
      int row = idx & 127, g = idx >> 7;
      int k = g & (h2-1), blk = g >> (lh-1);
      int base = row*LSTR + blk*(2*h1) + k;
      dif4(SR,SI,twr,twi, base, base+h2, base+h1, base+h1+h2,
           k << (6-lh), (k+h2) << (6-lh), k << (7-lh));
    }
    __syncthreads();
  }

  // ---- unpack: Z(bitrev slots) -> X[k] at slot rev6(k) (k=64 -> slot 64) ----
  for (int it = 0; it < 9; ++it) {
    int idx = t + 512*it;
    if (idx < 128*33) {
      int row = idx & 127, k = idx >> 7;   // k = 0..32
      int base = row*LSTR;
      if (k == 0) {
        float zr = SR[base], zi = SI[base];
        SR[base]    = zr + zi; SI[base]    = 0.f;   // X[0]
        SR[base+64] = zr - zi; SI[base+64] = 0.f;   // X[64]
      } else {
        int a = __brev((unsigned)k) >> 26;
        int bidx = __brev((unsigned)(64-k)) >> 26;
        float ar = SR[base+a], ai = SI[base+a];
        float br = SR[base+bidx], bi = SI[base+bidx];
        float sr_ = 0.5f*(ar+br), si_ = 0.5f*(ai-bi);
        float dr  = 0.5f*(ar-br), di  = 0.5f*(ai+bi);
        float wr = twr[k], wi = twi[k];
        float tr = wr*di + wi*dr;
        float ti = -(wr*dr - wi*di);
        SR[base+a]    = sr_ + tr; SI[base+a]    = si_ + ti;   // X[k]
        SR[base+bidx] = sr_ - tr; SI[base+bidx] = -si_ + ti;  // X[64-k]
      }
    }
  }
  __syncthreads();

  // ---- forward cols: 128-pt DIF over h, 65 columns ----
  #pragma unroll
  for (int ps = 0; ps < 3; ++ps) {
    const int lh = 6 - 2*ps;               // 6,4,2
    const int h1 = 1 << lh, h2 = h1 >> 1;
    for (int it = 0; it < 5; ++it) {
      int idx = t + 512*it;
      if (idx < 65*32) {
        int g = idx / 65, col = idx - g*65;
        int k = g & (h2-1), blk = g >> (lh-1);
        int p = blk*(2*h1) + k;
        dif4(SR,SI,twr,twi, p*LSTR+col, (p+h2)*LSTR+col, (p+h1)*LSTR+col, (p+h1+h2)*LSTR+col,
             k << (6-lh), (k+h2) << (6-lh), k << (7-lh));
      }
    }
    __syncthreads();
  }
  // final radix-2 (span 1, no twiddle)
  for (int it = 0; it < 9; ++it) {
    int idx = t + 512*it;
    if (idx < 65*64) {
      int j = idx / 65, col = idx - j*65;
      int a0 = (2*j)*LSTR + col, a1 = a0 + LSTR;
      float ur = SR[a0], ui = SI[a0], vr = SR[a1], vi = SI[a1];
      SR[a0]=ur+vr; SI[a0]=ui+vi; SR[a1]=ur-vr; SI[a1]=ui-vi;
    }
  }
  __syncthreads();

  // ---- routed spectral multiply (scale 1/8192 folds ortho^2 and the x2) ----
  {
    const float2* fb0 = (const float2*)filt + (size_t)(0*192+m)*8320;
    const float2* fb1 = (const float2*)filt + (size_t)(1*192+m)*8320;
    const float2* fb2 = (const float2*)filt + (size_t)(2*192+m)*8320;
    const float inv = 1.f/8192.f;
    for (int it = 0; it < 17; ++it) {
      int idx = t + 512*it;
      if (idx < 8320) {
        int fh = idx / 65, fw = idx - fh*65;
        float2 f0 = fb0[idx], f1 = fb1[idx], f2 = fb2[idx];
        float cr = (r0*f0.x + r1*f1.x + r2*f2.x) * inv;
        float ci = (r0*f0.y + r1*f1.y + r2*f2.y) * inv;
        int sh = __brev((unsigned)fh) >> 25;                       // rev7
        int sw = (fw == 64) ? 64 : (__brev((unsigned)fw) >> 26);   // rev6
        int a = sh*LSTR + sw;
        float xr = SR[a], xi = SI[a];
        SR[a] = xr*cr - xi*ci;
        SI[a] = xr*ci + xi*cr;
      }
    }
  }
  __syncthreads();

  // ---- inverse cols: 128-pt DIT ----
  #pragma unroll
  for (int ps = 0; ps < 3; ++ps) {
    const int la = 2*ps;                   // 0,2,4
    const int h = 1 << la;
    for (int it = 0; it < 5; ++it) {
      int idx = t + 512*it;
      if (idx < 65*32) {
        int g = idx / 65, col = idx - g*65;
        int k = g & (h-1), blk = g >> la;
        int p = blk*(4*h) + k;
        dit4(SR,SI,twr,twi, p*LSTR+col, (p+h)*LSTR+col, (p+2*h)*LSTR+col, (p+3*h)*LSTR+col,
             k << (6-la), k << (5-la), (k+h) << (5-la));
      }
    }
    __syncthreads();
  }
  // final radix-2 span 64 with conj twiddle
  for (int it = 0; it < 9; ++it) {
    int idx = t + 512*it;
    if (idx < 65*64) {
      int k = idx / 65, col = idx - k*65;
      int a0 = k*LSTR + col, a1 = a0 + 64*LSTR;
      float ur = SR[a0], ui = SI[a0], xr = SR[a1], xi = SI[a1];
      float wr = twr[k], wi = twi[k];
      float xtr = xr*wr + xi*wi, xti = xi*wr - xr*wi;   // x * conj(w)
      SR[a0]=ur+xtr; SI[a0]=ui+xti; SR[a1]=ur-xtr; SI[a1]=ui-xti;
    }
  }
  __syncthreads();

  // ---- pack: X (slots u(k)) -> Z[k] at slot rev6(k); drop imag at fw=0,64 ----
  for (int it = 0; it < 9; ++it) {
    int idx = t + 512*it;
    if (idx < 128*33) {
      int row = idx & 127, k = idx >> 7;
      int base = row*LSTR;
      if (k == 0) {
        float ar = SR[base];        // Re X[0]  (imag dropped)
        float cr = SR[base+64];     // Re X[64] (imag dropped)
        SR[base] = 0.5f*(ar+cr); SI[base] = 0.5f*(ar-cr);   // Z[0]
      } else {
        int a = __brev((unsigned)k) >> 26;
        int bidx = __brev((unsigned)(64-k)) >> 26;
        float ar = SR[base+a], ai = SI[base+a];
        float br = SR[base+bidx], bi = SI[base+bidx];
        float sr_ = 0.5f*(ar+br), si_ = 0.5f*(ai-bi);
        float dr  = 0.5f*(ar-br), di  = 0.5f*(ai+bi);
        float wr = twr[k], wi = twi[k];
        float tr2 = wi*dr - wr*di;
        float ti2 = wr*dr + wi*di;
        SR[base+a]    = sr_ + tr2; SI[base+a]    = si_ + ti2;   // Z[k]
        SR[base+bidx] = sr_ - tr2; SI[base+bidx] = -si_ + ti2;  // Z[64-k]
      }
    }
  }
  __syncthreads();

  // ---- inverse rows: 64-pt DIT ----
  #pragma unroll
  for (int ps = 0; ps < 3; ++ps) {
    const int la = 2*ps;                   // 0,2,4
    const int h = 1 << la;
    for (int it = 0; it < 4; ++it) {
      int idx = t + 512*it;
      int row = idx & 127, g = idx >> 7;
      int k = g & (h-1), blk = g >> la;
      int base = row*LSTR + blk*(4*h) + k;
      dit4(SR,SI,twr,twi, base, base+h, base+2*h, base+3*h,
           k << (6-la), k << (5-la), (k+h) << (5-la));
    }
    __syncthreads();
  }

  // ---- store: x[2n]=Re z[n], x[2n+1]=Im z[n] ----
  for (int it = 0; it < 8; ++it) {
    int idx = t + 512*it;
    int h = idx >> 5, j = idx & 31;
    int base = h*LSTR + 2*j;
    float4 v;
    v.x = SR[base];   v.y = SI[base];
    v.z = SR[base+1]; v.w = SI[base+1];
    ((float4*)plane)[idx] = v;
  }
}

// =====================================================================
// K_pw2: out[b,h,w,c] = sum_m xsp[b][m][h][w] * w2[c][m]  (unchanged)
// =====================================================================
__global__ __launch_bounds__(192) void k_pw2(
    const float* __restrict__ P, const float* __restrict__ w2, float* __restrict__ out)
{
  __shared__ __align__(16) float w2t[192*52];
  __shared__ __align__(16) float xs2[64*132];
  int t = threadIdx.x;
  int bx = blockIdx.x;
  int ch = bx & 1; int h = (bx >> 1) & 127; int b = bx >> 8;

  for (int i = t; i < 48*192; i += 192) {
    int c = i / 192, m = i % 192;
    w2t[m*52 + c] = w2[(ch*48 + c)*192 + m];
  }
  int wq4 = (t & 31)*4;
  int cg8 = (t >> 5)*8;
  float acc[4][8] = {};
  for (int mc = 0; mc < 3; ++mc) {
    __syncthreads();
    for (int i = t; i < 64*128/4; i += 192) {
      int flat = 4*i; int mm = flat >> 7; int w = flat & 127;
      float4 v = *(const float4*)&P[(size_t)(b*192 + mc*64 + mm)*HWPX + h*128 + w];
      *(float4*)&xs2[mm*132 + w] = v;
    }
    __syncthreads();
    for (int mm = 0; mm < 64; ++mm) {
      float4 xv = *(const float4*)&xs2[mm*132 + wq4];
      int mg = mc*64 + mm;
      float4 wa = *(const float4*)&w2t[mg*52 + cg8];
      float4 wb = *(const float4*)&w2t[mg*52 + cg8 + 4];
      float xa[4] = {xv.x,xv.y,xv.z,xv.w};
      float wv[8] = {wa.x,wa.y,wa.z,wa.w, wb.x,wb.y,wb.z,wb.w};
      #pragma unroll
      for (int ii=0;ii<4;ii++)
        #pragma unroll
        for (int jj=0;jj<8;jj++)
          acc[ii][jj] = fmaf(xa[ii], wv[jj], acc[ii][jj]);
    }
  }
  __syncthreads();
  #pragma unroll
  for (int wi=0; wi<4; wi++)
    #pragma unroll
    for (int cj=0; cj<8; cj++)
      xs2[(wq4+wi)*52 + cg8+cj] = acc[wi][cj];
  __syncthreads();
  for (int i = t; i < 128*48/4; i += 192) {
    int flat = 4*i; int w = flat / 48; int c = flat % 48;
    float4 v = *(const float4*)&xs2[w*52 + c];
    *(float4*)&out[((size_t)b*HWPX + h*128 + w)*96 + ch*48 + c] = v;
  }
}

// =====================================================================
extern "C" void kernel_launch(void* const* d_in, const int* in_sizes, int n_in,
                              void* d_out, int out_size, void* d_ws, size_t ws_size,
                              hipStream_t stream) {
  const float* x          = (const float*)d_in[0];
  const float* w1         = (const float*)d_in[1];
  const float* soa1_scale = (const float*)d_in[2];
  const float* soa1_bias  = (const float*)d_in[3];
  const float* cw0        = (const float*)d_in[4];
  const float* cw1        = (const float*)d_in[5];
  const float* cw2        = (const float*)d_in[6];
  const float* sp_w       = (const float*)d_in[7];
  const float* bn_gamma   = (const float*)d_in[8];
  const float* bn_beta    = (const float*)d_in[9];
  const float* bn_mean    = (const float*)d_in[10];
  const float* bn_var     = (const float*)d_in[11];
  const float* fc1        = (const float*)d_in[12];
  const float* mlp_scale  = (const float*)d_in[13];
  const float* mlp_bias   = (const float*)d_in[14];
  const float* fc2        = (const float*)d_in[15];
  const float* w2         = (const float*)d_in[16];
  float* out = (float*)d_out;

  float* ws   = (float*)d_ws;
  float* P    = ws + P_OFF;
  float* filt = ws + FILT_OFF;
  float* gsum = ws + GS_OFF;
  float* ssum = ws + SS_OFF;
  float* rbuf = ws + R_OFF;

  hipMemsetAsync(gsum, 0, (768+384)*sizeof(float), stream);

  k_route1 <<<512,  256, 0, stream>>>(x, sp_w, bn_gamma, bn_beta, bn_mean, bn_var, gsum, ssum);
  k_pw1    <<<3072, 256, 0, stream>>>(x, w1, soa1_scale, soa1_bias, P);
  k_route2 <<<8,    256, 0, stream>>>(gsum, ssum, fc1, fc2, mlp_scale, mlp_bias, rbuf);
  k_filt   <<<384,  256, 0, stream>>>(cw0, cw1, cw2, filt);
  k_spectral<<<1536,512, 0, stream>>>(P, filt, rbuf);
  k_pw2    <<<2048, 192, 0, stream>>>(P, w2, out);
}

// Round 3
// 431.862 us; speedup vs baseline: 1.9062x; 1.2719x over previous
//
#include <hip/hip_runtime.h>
#include <math.h>

// ---------------- problem constants ----------------
#define BB    8
#define HH    128
#define WW    128
#define DIM   96
#define MED   192
#define HWPX  16384        // H*W
#define FWH   65
#define LSTR  67           // LDS row stride (floats), odd -> conflict-free col walk

// workspace layout (float offsets)
#define P_OFF     0
#define P_SZ      (8*192*16384)            // x_pre / xsp planes [b][m][h][w]
#define FILT_OFF  (P_OFF + P_SZ)
#define FILT_SZ   (3*192*128*65*2)         // filt [s][m][fh][fw] complex
#define GS_OFF    (FILT_OFF + FILT_SZ)     // gctx sums  8*96
#define SS_OFF    (GS_OFF + 768)           // sctx sums  8*48
#define R_OFF     (SS_OFF + 384)           // r          8*3*192
#define W1B_OFF   (R_OFF + 4608)           // 36864 ushort = 18432 float slots
#define W2B_OFF   (W1B_OFF + 18432)        // 36864 ushort

typedef __attribute__((ext_vector_type(8))) short short8_t;
typedef __attribute__((ext_vector_type(4))) float float4_t;

__device__ __forceinline__ unsigned short bf16_rne(float f){
  unsigned u = __float_as_uint(f);
  unsigned r = (u + 0x7FFFu + ((u>>16)&1u)) >> 16;
  return (unsigned short)r;
}
__device__ __forceinline__ float bf16_to_f(unsigned short h){
  return __uint_as_float(((unsigned)h) << 16);
}

// =====================================================================
// K_prep: pack w1 / w2 into MFMA A/B fragment order, hi/lo bf16 split.
// W1B layout: [term(2)][kc(3)][nt(12)][lane(64)][j(8)]
//   A-role (w1): element = w1[m'=16nt+(lane&15)][c=32kc+(lane>>4)*8+j]
// W2B layout: [term(2)][kc(6)][nt(6)][lane(64)][j(8)]
//   B-role (w2): element = w2[c'=16nt+(lane&15)][m=32kc+(lane>>4)*8+j]
// =====================================================================
__global__ __launch_bounds__(256) void k_prep(
    const float* __restrict__ w1, const float* __restrict__ w2,
    unsigned short* __restrict__ W1B, unsigned short* __restrict__ W2B)
{
  int tid = threadIdx.x + blockIdx.x*256;
  int nthr = 256*36;
  for (int i = tid; i < 2*3*12*512; i += nthr) {
    int j = i & 7, l = (i>>3) & 63;
    int nt = (i>>9) % 12, kc = ((i>>9)/12) % 3, term = i / (3*12*512);
    int mp = nt*16 + (l&15);
    int c  = kc*32 + (l>>4)*8 + j;
    float v = w1[mp*96 + c];
    unsigned short hi = bf16_rne(v);
    W1B[i] = (term==0) ? hi : bf16_rne(v - bf16_to_f(hi));
  }
  for (int i = tid; i < 2*6*6*512; i += nthr) {
    int j = i & 7, l = (i>>3) & 63;
    int nt = (i>>9) % 6, kc = ((i>>9)/6) % 6, term = i / (6*6*512);
    int cp = nt*16 + (l&15);
    int m  = kc*32 + (l>>4)*8 + j;
    float v = w2[cp*192 + m];
    unsigned short hi = bf16_rne(v);
    W2B[i] = (term==0) ? hi : bf16_rne(v - bf16_to_f(hi));
  }
}

// =====================================================================
// K_route1: gctx partial sums + sctx partial sums  (unchanged)
// =====================================================================
__global__ __launch_bounds__(256) void k_route1(
    const float* __restrict__ x, const float* __restrict__ sp_w,
    const float* __restrict__ bn_gamma, const float* __restrict__ bn_beta,
    const float* __restrict__ bn_mean, const float* __restrict__ bn_var,
    float* __restrict__ gsum, float* __restrict__ ssum)
{
  __shared__ __align__(16) float xt[96*68];
  __shared__ __align__(16) float spwt[96*52];
  __shared__ float sacc[48];
  int t = threadIdx.x;
  int b = blockIdx.x >> 6;
  int chunk = blockIdx.x & 63;
  int p0 = chunk * 256;

  for (int i = t; i < 48*96; i += 256) { int s = i/96, c = i%96; spwt[c*52+s] = sp_w[i]; }
  if (t < 48) sacc[t] = 0.f;

  int sg  = t >> 4;
  int pi4 = (t & 15) * 4;
  float bnA[4], bnB[4];
  if (t < 192) {
    #pragma unroll
    for (int q=0;q<4;q++){
      int s = sg*4+q;
      float a = bn_gamma[s] * rsqrtf(bn_var[s] + 1e-5f);
      bnA[q]=a; bnB[q]=bn_beta[s] - bn_mean[s]*a;
    }
  }
  float greg = 0.f;
  float sreg[4] = {0.f,0.f,0.f,0.f};

  for (int tile = 0; tile < 4; ++tile) {
    __syncthreads();
    const float* src = x + ((size_t)b*HWPX + p0 + tile*64) * 96;
    for (int i = t; i < 64*96/4; i += 256) {
      float4 v = ((const float4*)src)[i];
      int flat = i*4; int p = flat/96, c = flat%96;
      xt[(c+0)*68+p]=v.x; xt[(c+1)*68+p]=v.y; xt[(c+2)*68+p]=v.z; xt[(c+3)*68+p]=v.w;
    }
    __syncthreads();
    if (t < 96) {
      const float4* col = (const float4*)&xt[t*68];
      float s0=0,s1=0,s2=0,s3=0;
      #pragma unroll
      for (int j=0;j<16;j++){ float4 v = col[j]; s0+=v.x; s1+=v.y; s2+=v.z; s3+=v.w; }
      greg += (s0+s1)+(s2+s3);
    }
    if (t < 192) {
      float acc[4][4] = {};
      for (int c = 0; c < 96; ++c) {
        float4 xv = *(const float4*)&xt[c*68 + pi4];
        float4 wv = *(const float4*)&spwt[c*52 + sg*4];
        float xa[4] = {xv.x,xv.y,xv.z,xv.w};
        float wa[4] = {wv.x,wv.y,wv.z,wv.w};
        #pragma unroll
        for (int ii=0;ii<4;ii++)
          #pragma unroll
          for (int jj=0;jj<4;jj++)
            acc[ii][jj] = fmaf(xa[ii], wa[jj], acc[ii][jj]);
      }
      #pragma unroll
      for (int q=0;q<4;q++)
        #pragma unroll
        for (int pp=0;pp<4;pp++) {
          float yb = acc[pp][q]*bnA[q] + bnB[q];
          sreg[q] += fmaxf(yb, 0.f);
        }
    }
  }
  __syncthreads();
  if (t < 192) { for (int q=0;q<4;q++) atomicAdd(&sacc[sg*4+q], sreg[q]); }
  if (t < 96) atomicAdd(&gsum[b*96+t], greg);
  __syncthreads();
  if (t < 48) atomicAdd(&ssum[b*48+t], sacc[t]);
}

// =====================================================================
// K_pw1 (MFMA): P[b][m'][px] = Soa( w1[m'][c] . x[px][c] )
// A = w1 (rows=m', frag-packed in W1B), B = x (cols=px, built in regs),
// hi/lo split-bf16, 3 MFMAs per tile. Zero LDS. 64 px/block, 4 waves.
// =====================================================================
__global__ __launch_bounds__(256) void k_pw1(
    const float* __restrict__ x, const unsigned short* __restrict__ W1B,
    const float* __restrict__ soa_scale, const float* __restrict__ soa_bias,
    float* __restrict__ P)
{
  int t = threadIdx.x;
  int lane = t & 63, wv = t >> 6;
  int px0 = blockIdx.x*64 + wv*16;        // global flat pixel base for this wave
  int b = px0 >> 14;
  int pxl = px0 & 16383;                  // within-plane offset

  float4_t acc[12];
  #pragma unroll
  for (int nt=0; nt<12; ++nt) acc[nt] = (float4_t){0.f,0.f,0.f,0.f};

  #pragma unroll
  for (int kc=0; kc<3; ++kc) {
    // B-frag: x[px0+(lane&15)][kc*32 + (lane>>4)*8 + j], j=0..7
    const float* xp = x + (size_t)(px0 + (lane&15))*96 + kc*32 + (lane>>4)*8;
    float4 v0 = *(const float4*)xp;
    float4 v1 = *(const float4*)(xp+4);
    float vv[8] = {v0.x,v0.y,v0.z,v0.w, v1.x,v1.y,v1.z,v1.w};
    short8_t Bh, Bl;
    #pragma unroll
    for (int j=0;j<8;j++){
      unsigned short h = bf16_rne(vv[j]);
      Bh[j] = (short)h;
      Bl[j] = (short)bf16_rne(vv[j] - bf16_to_f(h));
    }
    const short8_t* a_hi = (const short8_t*)(W1B + (size_t)(0*3+kc)*12*512) + lane;
    const short8_t* a_lo = (const short8_t*)(W1B + (size_t)(1*3+kc)*12*512) + lane;
    #pragma unroll
    for (int nt=0; nt<12; ++nt) {
      short8_t Ah = a_hi[nt*64];
      short8_t Al = a_lo[nt*64];
      acc[nt] = __builtin_amdgcn_mfma_f32_16x16x32_bf16(Ah, Bh, acc[nt], 0,0,0);
      acc[nt] = __builtin_amdgcn_mfma_f32_16x16x32_bf16(Ah, Bl, acc[nt], 0,0,0);
      acc[nt] = __builtin_amdgcn_mfma_f32_16x16x32_bf16(Al, Bh, acc[nt], 0,0,0);
    }
  }
  float sc = soa_scale[0], bi = soa_bias[0];
  // D: row=(lane>>4)*4+q = m'-offset, col=lane&15 = px-offset
  #pragma unroll
  for (int nt=0; nt<12; ++nt) {
    #pragma unroll
    for (int q=0;q<4;q++){
      float d = acc[nt][q];
      float v = fmaxf(d, 0.f);
      d = sc*v*v + bi;
      int mp = nt*16 + (lane>>4)*4 + q;
      P[(size_t)(b*192 + mp)*HWPX + pxl + (lane&15)] = d;
    }
  }
}

// =====================================================================
// K_pw2 (MFMA): out[px][c'] = xsp[m][px] . w2[c'][m]
// A = xsp (rows=px, built in regs from planar), B = w2 (cols=c', W2B).
// =====================================================================
__global__ __launch_bounds__(256) void k_pw2(
    const float* __restrict__ P, const unsigned short* __restrict__ W2B,
    float* __restrict__ out)
{
  int t = threadIdx.x;
  int lane = t & 63, wv = t >> 6;
  int px0 = blockIdx.x*64 + wv*16;
  int b = px0 >> 14;
  int pxl = px0 & 16383;

  float4_t acc[6];
  #pragma unroll
  for (int nt=0; nt<6; ++nt) acc[nt] = (float4_t){0.f,0.f,0.f,0.f};

  #pragma unroll
  for (int kc=0; kc<6; ++kc) {
    // A-frag: xsp[m = kc*32 + (lane>>4)*8 + j][px0 + (lane&15)]
    const float* ap = P + (size_t)(b*192 + kc*32 + (lane>>4)*8)*HWPX + pxl + (lane&15);
    short8_t Ah, Al;
    #pragma unroll
    for (int j=0;j<8;j++){
      float v = ap[(size_t)j*HWPX];
      unsigned short h = bf16_rne(v);
      Ah[j] = (short)h;
      Al[j] = (short)bf16_rne(v - bf16_to_f(h));
    }
    const short8_t* b_hi = (const short8_t*)(W2B + (size_t)(0*6+kc)*6*512) + lane;
    const short8_t* b_lo = (const short8_t*)(W2B + (size_t)(1*6+kc)*6*512) + lane;
    #pragma unroll
    for (int nt=0; nt<6; ++nt) {
      short8_t Bh = b_hi[nt*64];
      short8_t Bl = b_lo[nt*64];
      acc[nt] = __builtin_amdgcn_mfma_f32_16x16x32_bf16(Ah, Bh, acc[nt], 0,0,0);
      acc[nt] = __builtin_amdgcn_mfma_f32_16x16x32_bf16(Ah, Bl, acc[nt], 0,0,0);
      acc[nt] = __builtin_amdgcn_mfma_f32_16x16x32_bf16(Al, Bh, acc[nt], 0,0,0);
    }
  }
  // D: row=(lane>>4)*4+q = px-offset, col=lane&15 = c'-offset
  #pragma unroll
  for (int nt=0; nt<6; ++nt) {
    #pragma unroll
    for (int q=0;q<4;q++){
      int px = px0 + (lane>>4)*4 + q;
      out[(size_t)px*96 + nt*16 + (lane&15)] = acc[nt][q];
    }
  }
}

// =====================================================================
// K_route2: per-batch MLP + softmax routing weights (unchanged)
// =====================================================================
__global__ __launch_bounds__(256) void k_route2(
    const float* __restrict__ gsum, const float* __restrict__ ssum,
    const float* __restrict__ fc1, const float* __restrict__ fc2,
    const float* __restrict__ mlp_scale, const float* __restrict__ mlp_bias,
    float* __restrict__ r_out)
{
  __shared__ float fused[144], hmid[36], rpre[576];
  int t = threadIdx.x, b = blockIdx.x;
  if (t < 96) fused[t] = gsum[b*96+t] * (1.f/16384.f);
  else if (t < 144) fused[t] = ssum[b*48 + (t-96)] * (1.f/16384.f);
  __syncthreads();
  if (t < 36) {
    float a = 0.f;
    for (int i=0;i<144;i++) a = fmaf(fused[i], fc1[t*144+i], a);
    float rr = fmaxf(a, 0.f);
    hmid[t] = mlp_scale[0]*rr*rr + mlp_bias[0];
  }
  __syncthreads();
  for (int o = t; o < 576; o += 256) {
    float a = 0.f;
    for (int j=0;j<36;j++) a = fmaf(hmid[j], fc2[o*36+j], a);
    rpre[o] = a;
  }
  __syncthreads();
  if (t < 192) {
    float v0 = rpre[t], v1 = rpre[192+t], v2 = rpre[384+t];
    float mx = fmaxf(v0, fmaxf(v1, v2));
    float e0 = expf(v0-mx), e1 = expf(v1-mx), e2 = expf(v2-mx);
    float inv = 1.f/(e0+e1+e2);
    r_out[(b*3+0)*192+t] = e0*inv;
    r_out[(b*3+1)*192+t] = e1*inv;
    r_out[(b*3+2)*192+t] = e2*inv;
  }
}

// =====================================================================
// K_filt: bicubic resize of cw_s to [128][65] (unchanged)
// =====================================================================
__device__ __forceinline__ float cubicw(float tt){
  float t = fabsf(tt), t2=t*t, t3=t2*t;
  if (t <= 1.f) return 1.25f*t3 - 2.25f*t2 + 1.f;
  if (t < 2.f)  return -0.75f*t3 + 3.75f*t2 - 6.f*t + 3.f;
  return 0.f;
}

__global__ __launch_bounds__(256) void k_filt(
    const float* __restrict__ cw0, const float* __restrict__ cw1,
    const float* __restrict__ cw2, float* __restrict__ filt)
{
  int bx = blockIdx.x; int s = bx >> 7; int fh = bx & 127;
  const float* cw = (s==0) ? cw0 : ((s==1) ? cw1 : cw2);
  int SH = (s==0) ? 16 : ((s==1) ? 8 : 24);
  int SW = (s==0) ? 9  : ((s==1) ? 4 : 13);
  float sh = fh * (float)(SH-1) / 127.f;
  int fh0 = (int)floorf(sh);
  float wh[4]; int ih[4];
  #pragma unroll
  for (int k=0;k<4;k++){
    int kk = fh0-1+k;
    wh[k] = cubicw(sh - (float)kk);
    ih[k] = min(max(kk,0), SH-1);
  }
  int t = threadIdx.x;
  for (int i = t; i < 192*65; i += 256) {
    int m = i / 65, fw = i % 65;
    float sw = fw * (float)(SW-1) / 64.f;
    int fw0 = (int)floorf(sw);
    float are=0.f, aim=0.f;
    #pragma unroll
    for (int kb=0;kb<4;kb++){
      int jj = fw0-1+kb;
      float wwb = cubicw(sw - (float)jj);
      int iw = min(max(jj,0), SW-1);
      #pragma unroll
      for (int ka=0;ka<4;ka++){
        const float* p = cw + (size_t)((ih[ka]*SW + iw)*192 + m)*2;
        float wgt = wh[ka]*wwb;
        are = fmaf(wgt, p[0], are);
        aim = fmaf(wgt, p[1], aim);
      }
    }
    *(float2*)&filt[ (size_t)(((s*192+m)*128 + fh)*65 + fw) * 2 ] = make_float2(are, aim);
  }
}

// =====================================================================
// K_spectral: unchanged from round 2 (verified).
// =====================================================================
__device__ __forceinline__ void dif4(float* SR, float* SI,
    const float* twr, const float* twi,
    int a0, int a1, int a2, int a3, int t1, int t2, int t3)
{
  float x0r=SR[a0], x0i=SI[a0], x1r=SR[a1], x1i=SI[a1];
  float x2r=SR[a2], x2i=SI[a2], x3r=SR[a3], x3i=SI[a3];
  float ur = x0r+x2r, ui = x0i+x2i, d0r = x0r-x2r, d0i = x0i-x2i;
  float sr = x1r+x3r, si = x1i+x3i, d1r = x1r-x3r, d1i = x1i-x3i;
  float w1r = twr[t1], w1i = twi[t1];
  float wr_ = d0r*w1r - d0i*w1i, wi_ = d0r*w1i + d0i*w1r;
  float w2r = twr[t2], w2i = twi[t2];
  float vr = d1r*w2r - d1i*w2i, vi = d1r*w2i + d1i*w2r;
  float t3r = twr[t3], t3i = twi[t3];
  SR[a0] = ur+sr;  SI[a0] = ui+si;
  float mr = ur-sr, mi = ui-si;
  SR[a1] = mr*t3r - mi*t3i; SI[a1] = mr*t3i + mi*t3r;
  SR[a2] = wr_+vr; SI[a2] = wi_+vi;
  float nr = wr_-vr, ni = wi_-vi;
  SR[a3] = nr*t3r - ni*t3i; SI[a3] = nr*t3i + ni*t3r;
}

__device__ __forceinline__ void dit4(float* SR, float* SI,
    const float* twr, const float* twi,
    int a0, int a1, int a2, int a3, int tA, int tB, int tC)
{
  float x0r=SR[a0], x0i=SI[a0], x1r=SR[a1], x1i=SI[a1];
  float x2r=SR[a2], x2i=SI[a2], x3r=SR[a3], x3i=SI[a3];
  float war = twr[tA], wai = twi[tA];
  float x1tr = x1r*war + x1i*wai, x1ti = x1i*war - x1r*wai;
  float x3tr = x3r*war + x3i*wai, x3ti = x3i*war - x3r*wai;
  float ur = x0r+x1tr, ui = x0i+x1ti, vr = x0r-x1tr, vi = x0i-x1ti;
  float sr = x2r+x3tr, si = x2i+x3ti, wr_ = x2r-x3tr, wi_ = x2i-x3ti;
  float wbr = twr[tB], wbi = twi[tB];
  float str = sr*wbr + si*wbi, sti = si*wbr - sr*wbi;
  float wcr = twr[tC], wci = twi[tC];
  float wtr = wr_*wcr + wi_*wci, wti = wi_*wcr - wr_*wci;
  SR[a0] = ur+str; SI[a0] = ui+sti;
  SR[a2] = ur-str; SI[a2] = ui-sti;
  SR[a1] = vr+wtr; SI[a1] = vi+wti;
  SR[a3] = vr-wtr; SI[a3] = vi-wti;
}

__global__ __launch_bounds__(512, 4) void k_spectral(
    float* __restrict__ P, const float* __restrict__ filt, const float* __restrict__ r)
{
  __shared__ float SR[128*LSTR];
  __shared__ float SI[128*LSTR];
  __shared__ float twr[64], twi[64];
  int t = threadIdx.x;
  int bm = blockIdx.x; int b = bm / 192; int m = bm % 192;
  float* plane = P + (size_t)bm * HWPX;

  if (t < 64) {
    float ang = -6.283185307179586477f * (float)t / 128.f;
    twr[t] = cosf(ang); twi[t] = sinf(ang);
  }
  for (int it = 0; it < 8; ++it) {
    int idx = t + 512*it;
    int h = idx >> 5, j = idx & 31;
    float4 v = ((const float4*)plane)[idx];
    int base = h*LSTR + 2*j;
    SR[base]   = v.x; SI[base]   = v.y;
    SR[base+1] = v.z; SI[base+1] = v.w;
  }
  float r0 = r[(b*3+0)*192+m];
  float r1 = r[(b*3+1)*192+m];
  float r2 = r[(b*3+2)*192+m];
  __syncthreads();

  #pragma unroll
  for (int ps = 0; ps < 3; ++ps) {
    const int lh = 5 - 2*ps;
    const int h1 = 1 << lh, h2 = h1 >> 1;
    for (int it = 0; it < 4; ++it) {
      int idx = t + 512*it;
      int row = idx & 127, g = idx >> 7;
      int k = g & (h2-1), blk = g >> (lh-1);
      int base = row*LSTR + blk*(2*h1) + k;
      dif4(SR,SI,twr,twi, base, base+h2, base+h1, base+h1+h2,
           k << (6-lh), (k+h2) << (6-lh), k << (7-lh));
    }
    __syncthreads();
  }

  for (int it = 0; it < 9; ++it) {
    int idx = t + 512*it;
    if (idx < 128*33) {
      int row = idx & 127, k = idx >> 7;
      int base = row*LSTR;
      if (k == 0) {
        float zr = SR[base], zi = SI[base];
        SR[base]    = zr + zi; SI[base]    = 0.f;
        SR[base+64] = zr - zi; SI[base+64] = 0.f;
      } else {
        int a = __brev((unsigned)k) >> 26;
        int bidx = __brev((unsigned)(64-k)) >> 26;
        float ar = SR[base+a], ai = SI[base+a];
        float br = SR[base+bidx], bi = SI[base+bidx];
        float sr_ = 0.5f*(ar+br), si_ = 0.5f*(ai-bi);
        float dr  = 0.5f*(ar-br), di  = 0.5f*(ai+bi);
        float wr = twr[k], wi = twi[k];
        float tr = wr*di + wi*dr;
        float ti = -(wr*dr - wi*di);
        SR[base+a]    = sr_ + tr; SI[base+a]    = si_ + ti;
        SR[base+bidx] = sr_ - tr; SI[base+bidx] = -si_ + ti;
      }
    }
  }
  __syncthreads();

  #pragma unroll
  for (int ps = 0; ps < 3; ++ps) {
    const int lh = 6 - 2*ps;
    const int h1 = 1 << lh, h2 = h1 >> 1;
    for (int it = 0; it < 5; ++it) {
      int idx = t + 512*it;
      if (idx < 65*32) {
        int g = idx / 65, col = idx - g*65;
        int k = g & (h2-1), blk = g >> (lh-1);
        int p = blk*(2*h1) + k;
        dif4(SR,SI,twr,twi, p*LSTR+col, (p+h2)*LSTR+col, (p+h1)*LSTR+col, (p+h1+h2)*LSTR+col,
             k << (6-lh), (k+h2) << (6-lh), k << (7-lh));
      }
    }
    __syncthreads();
  }
  for (int it = 0; it < 9; ++it) {
    int idx = t + 512*it;
    if (idx < 65*64) {
      int j = idx / 65, col = idx - j*65;
      int a0 = (2*j)*LSTR + col, a1 = a0 + LSTR;
      float ur = SR[a0], ui = SI[a0], vr = SR[a1], vi = SI[a1];
      SR[a0]=ur+vr; SI[a0]=ui+vi; SR[a1]=ur-vr; SI[a1]=ui-vi;
    }
  }
  __syncthreads();

  {
    const float2* fb0 = (const float2*)filt + (size_t)(0*192+m)*8320;
    const float2* fb1 = (const float2*)filt + (size_t)(1*192+m)*8320;
    const float2* fb2 = (const float2*)filt + (size_t)(2*192+m)*8320;
    const float inv = 1.f/8192.f;
    for (int it = 0; it < 17; ++it) {
      int idx = t + 512*it;
      if (idx < 8320) {
        int fh = idx / 65, fw = idx - fh*65;
        float2 f0 = fb0[idx], f1 = fb1[idx], f2 = fb2[idx];
        float cr = (r0*f0.x + r1*f1.x + r2*f2.x) * inv;
        float ci = (r0*f0.y + r1*f1.y + r2*f2.y) * inv;
        int sh = __brev((unsigned)fh) >> 25;
        int sw = (fw == 64) ? 64 : (__brev((unsigned)fw) >> 26);
        int a = sh*LSTR + sw;
        float xr = SR[a], xi = SI[a];
        SR[a] = xr*cr - xi*ci;
        SI[a] = xr*ci + xi*cr;
      }
    }
  }
  __syncthreads();

  #pragma unroll
  for (int ps = 0; ps < 3; ++ps) {
    const int la = 2*ps;
    const int h = 1 << la;
    for (int it = 0; it < 5; ++it) {
      int idx = t + 512*it;
      if (idx < 65*32) {
        int g = idx / 65, col = idx - g*65;
        int k = g & (h-1), blk = g >> la;
        int p = blk*(4*h) + k;
        dit4(SR,SI,twr,twi, p*LSTR+col, (p+h)*LSTR+col, (p+2*h)*LSTR+col, (p+3*h)*LSTR+col,
             k << (6-la), k << (5-la), (k+h) << (5-la));
      }
    }
    __syncthreads();
  }
  for (int it = 0; it < 9; ++it) {
    int idx = t + 512*it;
    if (idx < 65*64) {
      int k = idx / 65, col = idx - k*65;
      int a0 = k*LSTR + col, a1 = a0 + 64*LSTR;
      float ur = SR[a0], ui = SI[a0], xr = SR[a1], xi = SI[a1];
      float wr = twr[k], wi = twi[k];
      float xtr = xr*wr + xi*wi, xti = xi*wr - xr*wi;
      SR[a0]=ur+xtr; SI[a0]=ui+xti; SR[a1]=ur-xtr; SI[a1]=ui-xti;
    }
  }
  __syncthreads();

  for (int it = 0; it < 9; ++it) {
    int idx = t + 512*it;
    if (idx < 128*33) {
      int row = idx & 127, k = idx >> 7;
      int base = row*LSTR;
      if (k == 0) {
        float ar = SR[base];
        float cr = SR[base+64];
        SR[base] = 0.5f*(ar+cr); SI[base] = 0.5f*(ar-cr);
      } else {
        int a = __brev((unsigned)k) >> 26;
        int bidx = __brev((unsigned)(64-k)) >> 26;
        float ar = SR[base+a], ai = SI[base+a];
        float br = SR[base+bidx], bi = SI[base+bidx];
        float sr_ = 0.5f*(ar+br), si_ = 0.5f*(ai-bi);
        float dr  = 0.5f*(ar-br), di  = 0.5f*(ai+bi);
        float wr = twr[k], wi = twi[k];
        float tr2 = wi*dr - wr*di;
        float ti2 = wr*dr + wi*di;
        SR[base+a]    = sr_ + tr2; SI[base+a]    = si_ + ti2;
        SR[base+bidx] = sr_ - tr2; SI[base+bidx] = -si_ + ti2;
      }
    }
  }
  __syncthreads();

  #pragma unroll
  for (int ps = 0; ps < 3; ++ps) {
    const int la = 2*ps;
    const int h = 1 << la;
    for (int it = 0; it < 4; ++it) {
      int idx = t + 512*it;
      int row = idx & 127, g = idx >> 7;
      int k = g & (h-1), blk = g >> la;
      int base = row*LSTR + blk*(4*h) + k;
      dit4(SR,SI,twr,twi, base, base+h, base+2*h, base+3*h,
           k << (6-la), k << (5-la), (k+h) << (5-la));
    }
    __syncthreads();
  }

  for (int it = 0; it < 8; ++it) {
    int idx = t + 512*it;
    int h = idx >> 5, j = idx & 31;
    int base = h*LSTR + 2*j;
    float4 v;
    v.x = SR[base];   v.y = SI[base];
    v.z = SR[base+1]; v.w = SI[base+1];
    ((float4*)plane)[idx] = v;
  }
}

// =====================================================================
extern "C" void kernel_launch(void* const* d_in, const int* in_sizes, int n_in,
                              void* d_out, int out_size, void* d_ws, size_t ws_size,
                              hipStream_t stream) {
  const float* x          = (const float*)d_in[0];
  const float* w1         = (const float*)d_in[1];
  const float* soa1_scale = (const float*)d_in[2];
  const float* soa1_bias  = (const float*)d_in[3];
  const float* cw0        = (const float*)d_in[4];
  const float* cw1        = (const float*)d_in[5];
  const float* cw2        = (const float*)d_in[6];
  const float* sp_w       = (const float*)d_in[7];
  const float* bn_gamma   = (const float*)d_in[8];
  const float* bn_beta    = (const float*)d_in[9];
  const float* bn_mean    = (const float*)d_in[10];
  const float* bn_var     = (const float*)d_in[11];
  const float* fc1        = (const float*)d_in[12];
  const float* mlp_scale  = (const float*)d_in[13];
  const float* mlp_bias   = (const float*)d_in[14];
  const float* fc2        = (const float*)d_in[15];
  const float* w2         = (const float*)d_in[16];
  float* out = (float*)d_out;

  float* ws   = (float*)d_ws;
  float* P    = ws + P_OFF;
  float* filt = ws + FILT_OFF;
  float* gsum = ws + GS_OFF;
  float* ssum = ws + SS_OFF;
  float* rbuf = ws + R_OFF;
  unsigned short* W1B = (unsigned short*)(ws + W1B_OFF);
  unsigned short* W2B = (unsigned short*)(ws + W2B_OFF);

  hipMemsetAsync(gsum, 0, (768+384)*sizeof(float), stream);

  k_prep   <<<36,   256, 0, stream>>>(w1, w2, W1B, W2B);
  k_route1 <<<512,  256, 0, stream>>>(x, sp_w, bn_gamma, bn_beta, bn_mean, bn_var, gsum, ssum);
  k_pw1    <<<2048, 256, 0, stream>>>(x, W1B, soa1_scale, soa1_bias, P);
  k_route2 <<<8,    256, 0, stream>>>(gsum, ssum, fc1, fc2, mlp_scale, mlp_bias, rbuf);
  k_filt   <<<384,  256, 0, stream>>>(cw0, cw1, cw2, filt);
  k_spectral<<<1536,512, 0, stream>>>(P, filt, rbuf);
  k_pw2    <<<2048, 256, 0, stream>>>(P, W2B, out);
}

// Round 4
// 419.692 us; speedup vs baseline: 1.9615x; 1.0290x over previous
//
#include <hip/hip_runtime.h>
#include <math.h>

// ---------------- problem constants ----------------
#define BB    8
#define HH    128
#define WW    128
#define DIM   96
#define MED   192
#define HWPX  16384        // H*W
#define FWH   65
#define LSTR  67           // LDS row stride in float2 units

// workspace layout (float offsets)
#define P_OFF     0
#define P_SZ      (8*192*16384)            // x_pre / xsp planes [b][m][h][w]
#define FILT_OFF  (P_OFF + P_SZ)
#define FILT_SZ   (3*192*128*65*2)         // filt [s][m][fh][fw] complex
#define GS_OFF    (FILT_OFF + FILT_SZ)     // gctx sums  8*96
#define SS_OFF    (GS_OFF + 768)           // sctx sums  8*48
#define R_OFF     (SS_OFF + 384)           // r          8*3*192
#define W1B_OFF   (R_OFF + 4608)           // 2*3*15*512 = 46080 ushort = 23040 float slots
#define W2B_OFF   (W1B_OFF + 23040)        // 36864 ushort

typedef __attribute__((ext_vector_type(8))) short short8_t;
typedef __attribute__((ext_vector_type(4))) float float4_t;

__device__ __forceinline__ unsigned short bf16_rne(float f){
  unsigned u = __float_as_uint(f);
  unsigned r = (u + 0x7FFFu + ((u>>16)&1u)) >> 16;
  return (unsigned short)r;
}
__device__ __forceinline__ float bf16_to_f(unsigned short h){
  return __uint_as_float(((unsigned)h) << 16);
}

// =====================================================================
// K_prep: pack [w1 ; sp_w] (15 tiles) and w2 into MFMA fragment order,
// hi/lo bf16 split.
// W1B: [term(2)][kc(3)][nt(15)][lane(64)][j(8)]
//   row r = nt*16+(lane&15): r<192 -> w1[r][c], else sp_w[r-192][c]
//   c = kc*32+(lane>>4)*8+j
// W2B: [term(2)][kc(6)][nt(6)][lane(64)][j(8)]  (unchanged)
// =====================================================================
__global__ __launch_bounds__(256) void k_prep(
    const float* __restrict__ w1, const float* __restrict__ sp_w,
    const float* __restrict__ w2,
    unsigned short* __restrict__ W1B, unsigned short* __restrict__ W2B)
{
  int tid = threadIdx.x + blockIdx.x*256;
  int nthr = 256*36;
  for (int i = tid; i < 2*3*15*512; i += nthr) {
    int j = i & 7, l = (i>>3) & 63;
    int nt = (i>>9) % 15, kc = ((i>>9)/15) % 3, term = i / (3*15*512);
    int r = nt*16 + (l&15);
    int c = kc*32 + (l>>4)*8 + j;
    float v = (r < 192) ? w1[r*96 + c] : sp_w[(r-192)*96 + c];
    unsigned short hi = bf16_rne(v);
    W1B[i] = (term==0) ? hi : bf16_rne(v - bf16_to_f(hi));
  }
  for (int i = tid; i < 2*6*6*512; i += nthr) {
    int j = i & 7, l = (i>>3) & 63;
    int nt = (i>>9) % 6, kc = ((i>>9)/6) % 6, term = i / (6*6*512);
    int cp = nt*16 + (l&15);
    int m  = kc*32 + (l>>4)*8 + j;
    float v = w2[cp*192 + m];
    unsigned short hi = bf16_rne(v);
    W2B[i] = (term==0) ? hi : bf16_rne(v - bf16_to_f(hi));
  }
}

// =====================================================================
// K_pw1 (MFMA, fused routing stats):
//  tiles 0..11 : P = Soa(w1 . x)  -> planar write
//  tiles 12..14: y = sp_w . x -> BN/relu -> px-sum -> ssum atomics
//  gctx: shfl-reduced fp32 x sums -> gsum atomics
// grid 2048 = 131072 px / 64 ; block 256 (4 waves x 16 px)
// =====================================================================
__global__ __launch_bounds__(256) void k_pw1(
    const float* __restrict__ x, const unsigned short* __restrict__ W1B,
    const float* __restrict__ soa_scale, const float* __restrict__ soa_bias,
    const float* __restrict__ bn_gamma, const float* __restrict__ bn_beta,
    const float* __restrict__ bn_mean, const float* __restrict__ bn_var,
    float* __restrict__ P, float* __restrict__ gsum, float* __restrict__ ssum)
{
  __shared__ float red[4][144];
  __shared__ float bnA_s[48], bnB_s[48];
  int t = threadIdx.x;
  int lane = t & 63, wv = t >> 6;
  if (t < 48) {
    float a = bn_gamma[t] * rsqrtf(bn_var[t] + 1e-5f);
    bnA_s[t] = a; bnB_s[t] = bn_beta[t] - bn_mean[t]*a;
  }
  int px0 = blockIdx.x*64 + wv*16;
  int b = (blockIdx.x*64) >> 14;
  int pxl = px0 & 16383;
  int g = lane >> 4;

  float4_t acc[15];
  #pragma unroll
  for (int nt=0; nt<15; ++nt) acc[nt] = (float4_t){0.f,0.f,0.f,0.f};

  #pragma unroll
  for (int kc=0; kc<3; ++kc) {
    const float* xp = x + (size_t)(px0 + (lane&15))*96 + kc*32 + g*8;
    float4 v0 = *(const float4*)xp;
    float4 v1 = *(const float4*)(xp+4);
    float vv[8] = {v0.x,v0.y,v0.z,v0.w, v1.x,v1.y,v1.z,v1.w};
    // gctx: sum over the wave's 16 px for c = kc*32+g*8+j
    #pragma unroll
    for (int j=0;j<8;j++){
      float s = vv[j];
      s += __shfl_xor(s, 1);
      s += __shfl_xor(s, 2);
      s += __shfl_xor(s, 4);
      s += __shfl_xor(s, 8);
      if ((lane & 15) == 0) red[wv][kc*32 + g*8 + j] = s;
    }
    short8_t Bh, Bl;
    #pragma unroll
    for (int j=0;j<8;j++){
      unsigned short h = bf16_rne(vv[j]);
      Bh[j] = (short)h;
      Bl[j] = (short)bf16_rne(vv[j] - bf16_to_f(h));
    }
    const short8_t* a_hi = (const short8_t*)(W1B + (size_t)(0*3+kc)*15*512) + lane;
    const short8_t* a_lo = (const short8_t*)(W1B + (size_t)(1*3+kc)*15*512) + lane;
    #pragma unroll
    for (int nt=0; nt<15; ++nt) {
      short8_t Ah = a_hi[nt*64];
      short8_t Al = a_lo[nt*64];
      acc[nt] = __builtin_amdgcn_mfma_f32_16x16x32_bf16(Ah, Bh, acc[nt], 0,0,0);
      acc[nt] = __builtin_amdgcn_mfma_f32_16x16x32_bf16(Ah, Bl, acc[nt], 0,0,0);
      acc[nt] = __builtin_amdgcn_mfma_f32_16x16x32_bf16(Al, Bh, acc[nt], 0,0,0);
    }
  }
  float sc = soa_scale[0], bi = soa_bias[0];
  // P write: tiles 0..11, D row=(g)*4+q = m'-offset, col=lane&15 = px
  #pragma unroll
  for (int nt=0; nt<12; ++nt) {
    #pragma unroll
    for (int q=0;q<4;q++){
      float d = acc[nt][q];
      float v = fmaxf(d, 0.f);
      d = sc*v*v + bi;
      int mp = nt*16 + g*4 + q;
      P[(size_t)(b*192 + mp)*HWPX + pxl + (lane&15)] = d;
    }
  }
  // sctx: tiles 12..14, BN+relu then px-sum
  #pragma unroll
  for (int tile=0; tile<3; ++tile) {
    #pragma unroll
    for (int q=0;q<4;q++){
      int s = tile*16 + g*4 + q;
      float y = acc[12+tile][q];
      float v = fmaxf(bnA_s[s]*y + bnB_s[s], 0.f);
      v += __shfl_xor(v, 1);
      v += __shfl_xor(v, 2);
      v += __shfl_xor(v, 4);
      v += __shfl_xor(v, 8);
      if ((lane & 15) == 0) red[wv][96 + s] = v;
    }
  }
  __syncthreads();
  if (t < 144) {
    float s = red[0][t] + red[1][t] + red[2][t] + red[3][t];
    if (t < 96) atomicAdd(&gsum[b*96 + t], s);
    else        atomicAdd(&ssum[b*48 + (t-96)], s);
  }
}

// =====================================================================
// K_pw2 (MFMA): out[px][c'] = xsp[m][px] . w2[c'][m]   (unchanged)
// =====================================================================
__global__ __launch_bounds__(256) void k_pw2(
    const float* __restrict__ P, const unsigned short* __restrict__ W2B,
    float* __restrict__ out)
{
  int t = threadIdx.x;
  int lane = t & 63, wv = t >> 6;
  int px0 = blockIdx.x*64 + wv*16;
  int b = px0 >> 14;
  int pxl = px0 & 16383;

  float4_t acc[6];
  #pragma unroll
  for (int nt=0; nt<6; ++nt) acc[nt] = (float4_t){0.f,0.f,0.f,0.f};

  #pragma unroll
  for (int kc=0; kc<6; ++kc) {
    const float* ap = P + (size_t)(b*192 + kc*32 + (lane>>4)*8)*HWPX + pxl + (lane&15);
    short8_t Ah, Al;
    #pragma unroll
    for (int j=0;j<8;j++){
      float v = ap[(size_t)j*HWPX];
      unsigned short h = bf16_rne(v);
      Ah[j] = (short)h;
      Al[j] = (short)bf16_rne(v - bf16_to_f(h));
    }
    const short8_t* b_hi = (const short8_t*)(W2B + (size_t)(0*6+kc)*6*512) + lane;
    const short8_t* b_lo = (const short8_t*)(W2B + (size_t)(1*6+kc)*6*512) + lane;
    #pragma unroll
    for (int nt=0; nt<6; ++nt) {
      short8_t Bh = b_hi[nt*64];
      short8_t Bl = b_lo[nt*64];
      acc[nt] = __builtin_amdgcn_mfma_f32_16x16x32_bf16(Ah, Bh, acc[nt], 0,0,0);
      acc[nt] = __builtin_amdgcn_mfma_f32_16x16x32_bf16(Ah, Bl, acc[nt], 0,0,0);
      acc[nt] = __builtin_amdgcn_mfma_f32_16x16x32_bf16(Al, Bh, acc[nt], 0,0,0);
    }
  }
  #pragma unroll
  for (int nt=0; nt<6; ++nt) {
    #pragma unroll
    for (int q=0;q<4;q++){
      int px = px0 + (lane>>4)*4 + q;
      out[(size_t)px*96 + nt*16 + (lane&15)] = acc[nt][q];
    }
  }
}

// =====================================================================
// K_route2: per-batch MLP + softmax routing weights (unchanged)
// =====================================================================
__global__ __launch_bounds__(256) void k_route2(
    const float* __restrict__ gsum, const float* __restrict__ ssum,
    const float* __restrict__ fc1, const float* __restrict__ fc2,
    const float* __restrict__ mlp_scale, const float* __restrict__ mlp_bias,
    float* __restrict__ r_out)
{
  __shared__ float fused[144], hmid[36], rpre[576];
  int t = threadIdx.x, b = blockIdx.x;
  if (t < 96) fused[t] = gsum[b*96+t] * (1.f/16384.f);
  else if (t < 144) fused[t] = ssum[b*48 + (t-96)] * (1.f/16384.f);
  __syncthreads();
  if (t < 36) {
    float a = 0.f;
    for (int i=0;i<144;i++) a = fmaf(fused[i], fc1[t*144+i], a);
    float rr = fmaxf(a, 0.f);
    hmid[t] = mlp_scale[0]*rr*rr + mlp_bias[0];
  }
  __syncthreads();
  for (int o = t; o < 576; o += 256) {
    float a = 0.f;
    for (int j=0;j<36;j++) a = fmaf(hmid[j], fc2[o*36+j], a);
    rpre[o] = a;
  }
  __syncthreads();
  if (t < 192) {
    float v0 = rpre[t], v1 = rpre[192+t], v2 = rpre[384+t];
    float mx = fmaxf(v0, fmaxf(v1, v2));
    float e0 = expf(v0-mx), e1 = expf(v1-mx), e2 = expf(v2-mx);
    float inv = 1.f/(e0+e1+e2);
    r_out[(b*3+0)*192+t] = e0*inv;
    r_out[(b*3+1)*192+t] = e1*inv;
    r_out[(b*3+2)*192+t] = e2*inv;
  }
}

// =====================================================================
// K_filt: bicubic resize of cw_s to [128][65] (unchanged)
// =====================================================================
__device__ __forceinline__ float cubicw(float tt){
  float t = fabsf(tt), t2=t*t, t3=t2*t;
  if (t <= 1.f) return 1.25f*t3 - 2.25f*t2 + 1.f;
  if (t < 2.f)  return -0.75f*t3 + 3.75f*t2 - 6.f*t + 3.f;
  return 0.f;
}

__global__ __launch_bounds__(256) void k_filt(
    const float* __restrict__ cw0, const float* __restrict__ cw1,
    const float* __restrict__ cw2, float* __restrict__ filt)
{
  int bx = blockIdx.x; int s = bx >> 7; int fh = bx & 127;
  const float* cw = (s==0) ? cw0 : ((s==1) ? cw1 : cw2);
  int SH = (s==0) ? 16 : ((s==1) ? 8 : 24);
  int SW = (s==0) ? 9  : ((s==1) ? 4 : 13);
  float sh = fh * (float)(SH-1) / 127.f;
  int fh0 = (int)floorf(sh);
  float wh[4]; int ih[4];
  #pragma unroll
  for (int k=0;k<4;k++){
    int kk = fh0-1+k;
    wh[k] = cubicw(sh - (float)kk);
    ih[k] = min(max(kk,0), SH-1);
  }
  int t = threadIdx.x;
  for (int i = t; i < 192*65; i += 256) {
    int m = i / 65, fw = i % 65;
    float sw = fw * (float)(SW-1) / 64.f;
    int fw0 = (int)floorf(sw);
    float are=0.f, aim=0.f;
    #pragma unroll
    for (int kb=0;kb<4;kb++){
      int jj = fw0-1+kb;
      float wwb = cubicw(sw - (float)jj);
      int iw = min(max(jj,0), SW-1);
      #pragma unroll
      for (int ka=0;ka<4;ka++){
        const float* p = cw + (size_t)((ih[ka]*SW + iw)*192 + m)*2;
        float wgt = wh[ka]*wwb;
        are = fmaf(wgt, p[0], are);
        aim = fmaf(wgt, p[1], aim);
      }
    }
    *(float2*)&filt[ (size_t)(((s*192+m)*128 + fh)*65 + fw) * 2 ] = make_float2(are, aim);
  }
}

// =====================================================================
// K_spectral: float2 LDS (b64) version of the verified round-2 FFT.
//  Same pass structure / math / write order; row passes remapped k-fast
//  so b64 accesses are exactly 4 lanes/bank (conflict-free).
//  m-major grid swizzle for filt L2 reuse.
// =====================================================================
__device__ __forceinline__ float2 c_add(float2 a, float2 b){ return make_float2(a.x+b.x, a.y+b.y); }
__device__ __forceinline__ float2 c_sub(float2 a, float2 b){ return make_float2(a.x-b.x, a.y-b.y); }
__device__ __forceinline__ float2 c_mul(float2 a, float2 w){ return make_float2(a.x*w.x - a.y*w.y, a.x*w.y + a.y*w.x); }
__device__ __forceinline__ float2 c_mulc(float2 a, float2 w){ return make_float2(a.x*w.x + a.y*w.y, a.y*w.x - a.x*w.y); }

__device__ __forceinline__ void dif4(float2* S, const float2* TW,
    int a0, int a1, int a2, int a3, int t1, int t2, int t3)
{
  float2 x0=S[a0], x1=S[a1], x2=S[a2], x3=S[a3];
  float2 u = c_add(x0,x2), d0 = c_sub(x0,x2);
  float2 s = c_add(x1,x3), d1 = c_sub(x1,x3);
  float2 w = c_mul(d0, TW[t1]);
  float2 v = c_mul(d1, TW[t2]);
  float2 t3w = TW[t3];
  S[a0] = c_add(u,s);
  S[a1] = c_mul(c_sub(u,s), t3w);
  S[a2] = c_add(w,v);
  S[a3] = c_mul(c_sub(w,v), t3w);
}

__device__ __forceinline__ void dit4(float2* S, const float2* TW,
    int a0, int a1, int a2, int a3, int tA, int tB, int tC)
{
  float2 x0=S[a0], x1=S[a1], x2=S[a2], x3=S[a3];
  float2 wA = TW[tA];
  float2 x1t = c_mulc(x1, wA), x3t = c_mulc(x3, wA);
  float2 u = c_add(x0,x1t), v = c_sub(x0,x1t);
  float2 s = c_add(x2,x3t), w = c_sub(x2,x3t);
  float2 st = c_mulc(s, TW[tB]);
  float2 wt = c_mulc(w, TW[tC]);
  S[a0] = c_add(u, st);
  S[a2] = c_sub(u, st);
  S[a1] = c_add(v, wt);
  S[a3] = c_sub(v, wt);
}

__global__ __launch_bounds__(512, 4) void k_spectral(
    float* __restrict__ P, const float* __restrict__ filt, const float* __restrict__ r)
{
  __shared__ float2 S[128*LSTR];   // 68,608 B
  __shared__ float2 TW[64];
  int t = threadIdx.x;
  int bm = blockIdx.x;
  int b = bm & 7; int m = bm >> 3;           // m-major for filt reuse
  float* plane = P + ((size_t)b*192 + m) * HWPX;

  if (t < 64) {
    float ang = -6.283185307179586477f * (float)t / 128.f;
    TW[t] = make_float2(cosf(ang), sinf(ang));
  }
  // load + even/odd pack: z[n] = x[2n] + i x[2n+1]
  for (int it = 0; it < 8; ++it) {
    int idx = t + 512*it;
    int h = idx >> 5, j = idx & 31;
    float4 v = ((const float4*)plane)[idx];
    int base = h*LSTR + 2*j;
    S[base]   = make_float2(v.x, v.y);
    S[base+1] = make_float2(v.z, v.w);
  }
  float r0 = r[(b*3+0)*192+m];
  float r1 = r[(b*3+1)*192+m];
  float r2 = r[(b*3+2)*192+m];
  __syncthreads();

  // ---- forward rows: 64-pt DIF, 3 radix-4 passes, k-fast mapping ----
  #pragma unroll
  for (int ps = 0; ps < 3; ++ps) {
    const int lh = 5 - 2*ps;               // 5,3,1
    const int h1 = 1 << lh, h2 = h1 >> 1;
    for (int it = 0; it < 4; ++it) {
      int idx = t + 512*it;                // 2048 = 128 rows * 16 groups
      int g = idx & 15, row = idx >> 4;
      int k = g & (h2-1), blk = g >> (lh-1);
      int base = row*LSTR + blk*(2*h1) + k;
      dif4(S,TW, base, base+h2, base+h1, base+h1+h2,
           k << (6-lh), (k+h2) << (6-lh), k << (7-lh));
    }
    __syncthreads();
  }

  // ---- unpack: 65-bin half spectrum (k=0..32; wave-uniform k) ----
  for (int it = 0; it < 9; ++it) {
    int idx = t + 512*it;
    if (idx < 128*33) {
      int row = idx & 127, k = idx >> 7;
      int base = row*LSTR;
      if (k == 0) {
        float2 z = S[base];
        S[base]    = make_float2(z.x + z.y, 0.f);
        S[base+64] = make_float2(z.x - z.y, 0.f);
      } else {
        int a = __brev((unsigned)k) >> 26;
        int bidx = __brev((unsigned)(64-k)) >> 26;
        float2 A = S[base+a], B = S[base+bidx];
        float sr_ = 0.5f*(A.x+B.x), si_ = 0.5f*(A.y-B.y);
        float dr  = 0.5f*(A.x-B.x), di  = 0.5f*(A.y+B.y);
        float2 w = TW[k];
        float tr = w.x*di + w.y*dr;
        float ti = -(w.x*dr - w.y*di);
        S[base+a]    = make_float2(sr_ + tr,  si_ + ti);
        S[base+bidx] = make_float2(sr_ - tr, -si_ + ti);
      }
    }
  }
  __syncthreads();

  // ---- forward cols: 128-pt DIF over h, 65 columns (col-fast) ----
  #pragma unroll
  for (int ps = 0; ps < 3; ++ps) {
    const int lh = 6 - 2*ps;               // 6,4,2
    const int h1 = 1 << lh, h2 = h1 >> 1;
    for (int it = 0; it < 5; ++it) {
      int idx = t + 512*it;
      if (idx < 65*32) {
        int g = idx / 65, col = idx - g*65;
        int k = g & (h2-1), blk = g >> (lh-1);
        int p = blk*(2*h1) + k;
        dif4(S,TW, p*LSTR+col, (p+h2)*LSTR+col, (p+h1)*LSTR+col, (p+h1+h2)*LSTR+col,
             k << (6-lh), (k+h2) << (6-lh), k << (7-lh));
      }
    }
    __syncthreads();
  }
  for (int it = 0; it < 9; ++it) {         // final radix-2 span 1
    int idx = t + 512*it;
    if (idx < 65*64) {
      int j = idx / 65, col = idx - j*65;
      int a0 = (2*j)*LSTR + col, a1 = a0 + LSTR;
      float2 u = S[a0], v = S[a1];
      S[a0] = c_add(u,v); S[a1] = c_sub(u,v);
    }
  }
  __syncthreads();

  // ---- routed spectral multiply (1/8192 folds ortho^2) ----
  {
    const float2* fb0 = (const float2*)filt + (size_t)(0*192+m)*8320;
    const float2* fb1 = (const float2*)filt + (size_t)(1*192+m)*8320;
    const float2* fb2 = (const float2*)filt + (size_t)(2*192+m)*8320;
    const float inv = 1.f/8192.f;
    for (int it = 0; it < 17; ++it) {
      int idx = t + 512*it;
      if (idx < 8320) {
        int fh = idx / 65, fw = idx - fh*65;
        float2 f0 = fb0[idx], f1 = fb1[idx], f2 = fb2[idx];
        float cr = (r0*f0.x + r1*f1.x + r2*f2.x) * inv;
        float ci = (r0*f0.y + r1*f1.y + r2*f2.y) * inv;
        int sh = __brev((unsigned)fh) >> 25;
        int sw = (fw == 64) ? 64 : (__brev((unsigned)fw) >> 26);
        int a = sh*LSTR + sw;
        float2 X = S[a];
        S[a] = make_float2(X.x*cr - X.y*ci, X.x*ci + X.y*cr);
      }
    }
  }
  __syncthreads();

  // ---- inverse cols: 128-pt DIT (col-fast) ----
  #pragma unroll
  for (int ps = 0; ps < 3; ++ps) {
    const int la = 2*ps;                   // 0,2,4
    const int h = 1 << la;
    for (int it = 0; it < 5; ++it) {
      int idx = t + 512*it;
      if (idx < 65*32) {
        int g = idx / 65, col = idx - g*65;
        int k = g & (h-1), blk = g >> la;
        int p = blk*(4*h) + k;
        dit4(S,TW, p*LSTR+col, (p+h)*LSTR+col, (p+2*h)*LSTR+col, (p+3*h)*LSTR+col,
             k << (6-la), k << (5-la), (k+h) << (5-la));
      }
    }
    __syncthreads();
  }
  for (int it = 0; it < 9; ++it) {         // final radix-2 span 64, conj tw
    int idx = t + 512*it;
    if (idx < 65*64) {
      int k = idx / 65, col = idx - k*65;
      int a0 = k*LSTR + col, a1 = a0 + 64*LSTR;
      float2 u = S[a0], xv = S[a1];
      float2 xt = c_mulc(xv, TW[k]);
      S[a0] = c_add(u,xt); S[a1] = c_sub(u,xt);
    }
  }
  __syncthreads();

  // ---- pack: drop imag at fw=0,64; back to packed z ----
  for (int it = 0; it < 9; ++it) {
    int idx = t + 512*it;
    if (idx < 128*33) {
      int row = idx & 127, k = idx >> 7;
      int base = row*LSTR;
      if (k == 0) {
        float ar = S[base].x;
        float cr = S[base+64].x;
        S[base] = make_float2(0.5f*(ar+cr), 0.5f*(ar-cr));
      } else {
        int a = __brev((unsigned)k) >> 26;
        int bidx = __brev((unsigned)(64-k)) >> 26;
        float2 A = S[base+a], B = S[base+bidx];
        float sr_ = 0.5f*(A.x+B.x), si_ = 0.5f*(A.y-B.y);
        float dr  = 0.5f*(A.x-B.x), di  = 0.5f*(A.y+B.y);
        float2 w = TW[k];
        float tr2 = w.y*dr - w.x*di;
        float ti2 = w.x*dr + w.y*di;
        S[base+a]    = make_float2(sr_ + tr2,  si_ + ti2);
        S[base+bidx] = make_float2(sr_ - tr2, -si_ + ti2);
      }
    }
  }
  __syncthreads();

  // ---- inverse rows: 64-pt DIT, k-fast mapping ----
  #pragma unroll
  for (int ps = 0; ps < 3; ++ps) {
    const int la = 2*ps;                   // 0,2,4
    const int h = 1 << la;
    for (int it = 0; it < 4; ++it) {
      int idx = t + 512*it;
      int g = idx & 15, row = idx >> 4;
      int k = g & (h-1), blk = g >> la;
      int base = row*LSTR + blk*(4*h) + k;
      dit4(S,TW, base, base+h, base+2*h, base+3*h,
           k << (6-la), k << (5-la), (k+h) << (5-la));
    }
    __syncthreads();
  }

  // ---- store ----
  for (int it = 0; it < 8; ++it) {
    int idx = t + 512*it;
    int h = idx >> 5, j = idx & 31;
    int base = h*LSTR + 2*j;
    float2 z0 = S[base], z1 = S[base+1];
    float4 v; v.x = z0.x; v.y = z0.y; v.z = z1.x; v.w = z1.y;
    ((float4*)plane)[idx] = v;
  }
}

// =====================================================================
extern "C" void kernel_launch(void* const* d_in, const int* in_sizes, int n_in,
                              void* d_out, int out_size, void* d_ws, size_t ws_size,
                              hipStream_t stream) {
  const float* x          = (const float*)d_in[0];
  const float* w1         = (const float*)d_in[1];
  const float* soa1_scale = (const float*)d_in[2];
  const float* soa1_bias  = (const float*)d_in[3];
  const float* cw0        = (const float*)d_in[4];
  const float* cw1        = (const float*)d_in[5];
  const float* cw2        = (const float*)d_in[6];
  const float* sp_w       = (const float*)d_in[7];
  const float* bn_gamma   = (const float*)d_in[8];
  const float* bn_beta    = (const float*)d_in[9];
  const float* bn_mean    = (const float*)d_in[10];
  const float* bn_var     = (const float*)d_in[11];
  const float* fc1        = (const float*)d_in[12];
  const float* mlp_scale  = (const float*)d_in[13];
  const float* mlp_bias   = (const float*)d_in[14];
  const float* fc2        = (const float*)d_in[15];
  const float* w2         = (const float*)d_in[16];
  float* out = (float*)d_out;

  float* ws   = (float*)d_ws;
  float* P    = ws + P_OFF;
  float* filt = ws + FILT_OFF;
  float* gsum = ws + GS_OFF;
  float* ssum = ws + SS_OFF;
  float* rbuf = ws + R_OFF;
  unsigned short* W1B = (unsigned short*)(ws + W1B_OFF);
  unsigned short* W2B = (unsigned short*)(ws + W2B_OFF);

  hipMemsetAsync(gsum, 0, (768+384)*sizeof(float), stream);

  k_prep   <<<36,   256, 0, stream>>>(w1, sp_w, w2, W1B, W2B);
  k_pw1    <<<2048, 256, 0, stream>>>(x, W1B, soa1_scale, soa1_bias,
                                      bn_gamma, bn_beta, bn_mean, bn_var,
                                      P, gsum, ssum);
  k_route2 <<<8,    256, 0, stream>>>(gsum, ssum, fc1, fc2, mlp_scale, mlp_bias, rbuf);
  k_filt   <<<384,  256, 0, stream>>>(cw0, cw1, cw2, filt);
  k_spectral<<<1536,512, 0, stream>>>(P, filt, rbuf);
  k_pw2    <<<2048, 256, 0, stream>>>(P, W2B, out);
}